// Round 2
// baseline (870.652 us; speedup 1.0000x reference)
//
#include <hip/hip_runtime.h>

// AttnHGCN.forward_ui — 3-layer bipartite LightGCN-style propagation.
// R7: replace the windowed direct scatter (190us, 7.4x write-amp, 2x
//     read-amp from write-allocate refetches of evicted partial CSR lines)
//     with a two-phase binned build:
//       (1) hist also counts ends per (wave, 16-window) -> scanned to
//           deterministic per-wave segment bases (no atomics),
//       (2) seg_write compacts each directed end into its window segment
//           (fully coalesced stores, packed (dstLow<<17|src, w)),
//       (3) scatter_fine x2 launches: per launch each XCD owns ONE 2MB CSR
//           window and reads only its own ~3MB segment -> window + stream
//           fit in the 4MB L2, lines fill before eviction.
//     Gathers reverted to the measured-best R5 form (unroll x2, plain loads).

constexpr int N_USERS = 100000;
constexpr int N_ITEMS = 50000;
constexpr int CH      = 64;
constexpr int N_EDGES = 2000000;
constexpr int LAYERS  = 3;
constexpr int NROWS   = N_USERS + N_ITEMS;          // 150000 combined dest rows
constexpr int NDIR    = 2 * N_EDGES;                // 4M directed edges

constexpr int QEDGES  = N_EDGES / 4;                // 500000 int4 edge-quads
constexpr int QBLK    = (QEDGES + 255) / 256;       // 1954 blocks over quads
constexpr int NWV     = QBLK * 4;                   // 7816 waves over quads

constexpr int WIN     = 16;                         // row windows
constexpr int WROWS16 = NROWS / WIN;                // 9375 rows per window
constexpr int NW16    = WIN * NWV;                  // 125056 (win,wave) counts

constexpr int FCHUNK  = 1024;                       // entries per fine block
constexpr int FBLKS   = 450;                        // covers <=460800/window (max ~376K)

constexpr long long ITEM_ELEMS = (long long)N_ITEMS * CH;  // 3,200,000
constexpr long long USER_ELEMS = (long long)N_USERS * CH;  // 6,400,000
constexpr long long TOT_ELEMS  = ITEM_ELEMS + USER_ELEMS;  // 9,600,000

typedef int   v4i __attribute__((ext_vector_type(4)));
typedef int   v2i __attribute__((ext_vector_type(2)));
typedef float v4f __attribute__((ext_vector_type(4)));

static __device__ __forceinline__ v2i nt_load2i(const void* p) {
  return __builtin_nontemporal_load((const v2i*)p);
}

// ---------------- CSR build ----------------

// Row histogram (global atomics) + per-(window, wave) end counts.
// No early return: all lanes participate in the shfl reductions.
__global__ __launch_bounds__(256) void hist_kernel(
    const int* __restrict__ u_idx, const int* __restrict__ i_idx,
    int* __restrict__ counts, int* __restrict__ blkwin) {
  int q = blockIdx.x * 256 + threadIdx.x;
  bool valid = (q < QEDGES);
  v4i u  = {0, 0, 0, 0};
  v4i it = {0, 0, 0, 0};
  if (valid) {
    u  = *(const v4i*)(u_idx + 4 * (long long)q);
    it = *(const v4i*)(i_idx + 4 * (long long)q);
  }
  if (valid) {
    atomicAdd(&counts[u.x], 1);
    atomicAdd(&counts[u.y], 1);
    atomicAdd(&counts[u.z], 1);
    atomicAdd(&counts[u.w], 1);
    atomicAdd(&counts[N_USERS + it.x], 1);
    atomicAdd(&counts[N_USERS + it.y], 1);
    atomicAdd(&counts[N_USERS + it.z], 1);
    atomicAdd(&counts[N_USERS + it.w], 1);
  }
  int rows[8];
  if (valid) {
    rows[0] = u.x; rows[1] = u.y; rows[2] = u.z; rows[3] = u.w;
    rows[4] = N_USERS + it.x; rows[5] = N_USERS + it.y;
    rows[6] = N_USERS + it.z; rows[7] = N_USERS + it.w;
  } else {
#pragma unroll
    for (int k = 0; k < 8; ++k) rows[k] = -1;
  }
  int lane = threadIdx.x & 63;
  int gw   = blockIdx.x * 4 + (threadIdx.x >> 6);
#pragma unroll
  for (int win = 0; win < WIN; ++win) {
    const int wlo = win * WROWS16;
    int c = 0;
#pragma unroll
    for (int k = 0; k < 8; ++k)
      c += ((unsigned)(rows[k] - wlo) < (unsigned)WROWS16) ? 1 : 0;
#pragma unroll
    for (int d = 1; d < 64; d <<= 1) c += __shfl_xor(c, d, 64);
    if (lane == 0) blkwin[win * NWV + gw] = c;
  }
}

// per-256-block exclusive scan; block sums out (generic)
__global__ __launch_bounds__(256) void scanA_kernel(
    const int* __restrict__ in, int* __restrict__ out,
    int* __restrict__ blksums, int n) {
  __shared__ int sh[256];
  int t = threadIdx.x;
  int i = blockIdx.x * 256 + t;
  int v = (i < n) ? in[i] : 0;
  int x = v;
  sh[t] = x; __syncthreads();
  for (int d = 1; d < 256; d <<= 1) {
    int add = (t >= d) ? sh[t - d] : 0;
    __syncthreads();
    x += add; sh[t] = x;
    __syncthreads();
  }
  if (i < n) out[i] = x - v;  // exclusive within block
  if (t == 255) blksums[blockIdx.x] = x;
}

// single-block exclusive scan of block sums (n2 <= 1024)
__global__ __launch_bounds__(1024) void scanB_kernel(int* __restrict__ blksums, int n2) {
  __shared__ int sh[1024];
  int t = threadIdx.x;
  int v = (t < n2) ? blksums[t] : 0;
  int x = v;
  sh[t] = x; __syncthreads();
  for (int d = 1; d < 1024; d <<= 1) {
    int add = (t >= d) ? sh[t - d] : 0;
    __syncthreads();
    x += add; sh[t] = x;
    __syncthreads();
  }
  if (t < n2) blksums[t] = x - v;  // exclusive
}

// add block offsets; init cursor; set terminator (row_ptr variant)
__global__ __launch_bounds__(256) void scanC_kernel(
    int* __restrict__ row_ptr, const int* __restrict__ blksums,
    int* __restrict__ cursor, int n) {
  int i = blockIdx.x * 256 + threadIdx.x;
  if (i < n) {
    int p = row_ptr[i] + blksums[i >> 8];
    row_ptr[i] = p;
    cursor[i] = p;
  }
  if (i == 0) row_ptr[n] = NDIR;
}

// add block offsets only (segment-offset variant)
__global__ __launch_bounds__(256) void winscanC_kernel(
    int* __restrict__ out, const int* __restrict__ blksums, int n) {
  int i = blockIdx.x * 256 + threadIdx.x;
  if (i < n) out[i] += blksums[i >> 8];
}

// Compact every directed end into its window's segment at a deterministic,
// wave-scanned position. All stores coalesced; zero atomics.
// Entry packing: x = (dstLow<<17) | src  (dstLow<9375 fits 14b, src<2^17),
//                y = float bits of w.
__global__ __launch_bounds__(256) void seg_write(
    const int* __restrict__ u_idx, const int* __restrict__ i_idx,
    const float* __restrict__ wv, const int* __restrict__ segoff,
    int2* __restrict__ seg) {
  int q = blockIdx.x * 256 + threadIdx.x;
  bool valid = (q < QEDGES);
  v4i u  = {0, 0, 0, 0};
  v4i it = {0, 0, 0, 0};
  v4f w  = {0.f, 0.f, 0.f, 0.f};
  if (valid) {
    u  = *(const v4i*)(u_idx + 4 * (long long)q);
    it = *(const v4i*)(i_idx + 4 * (long long)q);
    w  = *(const v4f*)(wv + 4 * (long long)q);
  }
  int rows[8], srcs[8], wbits[8];
  if (valid) {
    rows[0] = u.x; rows[1] = u.y; rows[2] = u.z; rows[3] = u.w;
    srcs[0] = it.x; srcs[1] = it.y; srcs[2] = it.z; srcs[3] = it.w;
    rows[4] = N_USERS + it.x; rows[5] = N_USERS + it.y;
    rows[6] = N_USERS + it.z; rows[7] = N_USERS + it.w;
    srcs[4] = u.x; srcs[5] = u.y; srcs[6] = u.z; srcs[7] = u.w;
    wbits[0] = __float_as_int(w.x); wbits[1] = __float_as_int(w.y);
    wbits[2] = __float_as_int(w.z); wbits[3] = __float_as_int(w.w);
    wbits[4] = wbits[0]; wbits[5] = wbits[1];
    wbits[6] = wbits[2]; wbits[7] = wbits[3];
  } else {
#pragma unroll
    for (int k = 0; k < 8; ++k) { rows[k] = -1; srcs[k] = 0; wbits[k] = 0; }
  }
  int lane = threadIdx.x & 63;
  int gw   = blockIdx.x * 4 + (threadIdx.x >> 6);
#pragma unroll
  for (int win = 0; win < WIN; ++win) {
    const int wlo = win * WROWS16;
    int c = 0;
#pragma unroll
    for (int k = 0; k < 8; ++k)
      c += ((unsigned)(rows[k] - wlo) < (unsigned)WROWS16) ? 1 : 0;
    // inclusive wave scan of c
    int x = c;
#pragma unroll
    for (int d = 1; d < 64; d <<= 1) {
      int y = __shfl_up(x, d, 64);
      if (lane >= d) x += y;
    }
    int pos = segoff[win * NWV + gw] + (x - c);  // exclusive prefix
#pragma unroll
    for (int k = 0; k < 8; ++k) {
      int dl = rows[k] - wlo;
      if ((unsigned)dl < (unsigned)WROWS16) {
        seg[pos++] = make_int2((dl << 17) | srcs[k], wbits[k]);
      }
    }
  }
}

// Fine scatter: per launch, XCD p (blockIdx%8) owns window wset*8+p: a 2MB
// CSR slot range + its own ~3MB segment stream -> both L2-resident, lines
// fill before eviction. Segment reads nt (read-once).
__global__ __launch_bounds__(256) void scatter_fine(
    const int2* __restrict__ seg, const int* __restrict__ segoff,
    int* __restrict__ cursor, int2* __restrict__ csr, int wset) {
  int pass  = blockIdx.x & 7;
  int win   = wset * 8 + pass;
  int chunk = blockIdx.x >> 3;
  int s0 = segoff[win * NWV];
  int s1 = (win < WIN - 1) ? segoff[(win + 1) * NWV] : NDIR;
  int base = s0 + chunk * FCHUNK + (int)threadIdx.x;
  if (base >= s1) return;
  const int wlo = win * WROWS16;
#pragma unroll
  for (int r = 0; r < 4; ++r) {
    int idx = base + r * 256;
    if (idx < s1) {
      v2i e = nt_load2i(seg + idx);
      int dstLow = ((unsigned)e.x) >> 17;
      int src = e.x & 0x1FFFF;
      int p = atomicAdd(&cursor[wlo + dstLow], 1);
      csr[p] = make_int2(src, e.y);
    }
  }
}

// ---------------- per-layer fused gather (R5 form) ----------------
// One wave per destination row; lane = slot(2b) x chan16(4b); adjacency loop
// unrolled x2 -> 8 edges (8x256B gathers) in flight per wave; butterfly-
// reduce slots. Epilogue fuses residual accumulation:
//   MODE 0 (layer 1):   dst = acc;  out = emb + acc
//   MODE 1 (mid layer): dst = acc;  out += acc
//   MODE 2 (last):                  out = (out + acc) * 1/(LAYERS+1)
template <int MODE>
__global__ __launch_bounds__(256) void gather_fused(
    const float* __restrict__ it_tab,  // gather-source item table
    const float* __restrict__ u_tab,   // gather-source user table
    float* __restrict__ dst,           // [it|u] layer output (MODE<2)
    float* __restrict__ out,           // [item_acc | user_acc]
    const int2* __restrict__ csr,
    const int* __restrict__ row_ptr) {
  int row = blockIdx.x * 4 + (threadIdx.x >> 6);
  if (row >= NROWS) return;
  int lane = threadIdx.x & 63;
  int slot = lane >> 4;          // 0..3
  int c4   = (lane & 15) * 4;    // channel offset 0..60

  const float* gtab;             // opposite-side table to gather from
  const float* erow = nullptr;   // dest-side input-emb row (MODE 0)
  float* drow = nullptr;
  float* orow;
  if (row < N_USERS) {
    gtab = it_tab;
    orow = out + ITEM_ELEMS + (long long)row * CH;
    if (MODE < 2)  drow = dst + ITEM_ELEMS + (long long)row * CH;
    if (MODE == 0) erow = u_tab + (long long)row * CH;  // u_tab==user_emb here
  } else {
    int r = row - N_USERS;
    gtab = u_tab;
    orow = out + (long long)r * CH;
    if (MODE < 2)  drow = dst + (long long)r * CH;
    if (MODE == 0) erow = it_tab + (long long)r * CH;   // it_tab==item_emb here
  }

  int beg = row_ptr[row], end = row_ptr[row + 1];
  float4 acc = make_float4(0.f, 0.f, 0.f, 0.f);
  int j = beg + slot;
  // unrolled x2: two independent (csr, row) load pairs in flight
  for (; j + 4 < end; j += 8) {
    int2  e0 = csr[j];
    int2  e1 = csr[j + 4];
    float4 v0 = *(const float4*)(gtab + (long long)e0.x * CH + c4);
    float4 v1 = *(const float4*)(gtab + (long long)e1.x * CH + c4);
    float w0 = __int_as_float(e0.y);
    float w1 = __int_as_float(e1.y);
    acc.x += w0 * v0.x; acc.y += w0 * v0.y;
    acc.z += w0 * v0.z; acc.w += w0 * v0.w;
    acc.x += w1 * v1.x; acc.y += w1 * v1.y;
    acc.z += w1 * v1.z; acc.w += w1 * v1.w;
  }
  if (j < end) {
    int2  e  = csr[j];
    float we = __int_as_float(e.y);
    float4 v = *(const float4*)(gtab + (long long)e.x * CH + c4);
    acc.x += we * v.x; acc.y += we * v.y;
    acc.z += we * v.z; acc.w += we * v.w;
  }
  for (int off = 16; off < 64; off <<= 1) {
    acc.x += __shfl_xor(acc.x, off, 64);
    acc.y += __shfl_xor(acc.y, off, 64);
    acc.z += __shfl_xor(acc.z, off, 64);
    acc.w += __shfl_xor(acc.w, off, 64);
  }
  if (slot == 0) {
    if (MODE == 0) {
      float4 e4 = *(const float4*)(erow + c4);
      *(float4*)(drow + c4) = acc;
      e4.x += acc.x; e4.y += acc.y; e4.z += acc.z; e4.w += acc.w;
      *(float4*)(orow + c4) = e4;
    } else if (MODE == 1) {
      float4 o = *(const float4*)(orow + c4);
      *(float4*)(drow + c4) = acc;
      o.x += acc.x; o.y += acc.y; o.z += acc.z; o.w += acc.w;
      *(float4*)(orow + c4) = o;
    } else {
      const float s = 1.0f / (LAYERS + 1);
      float4 o = *(const float4*)(orow + c4);
      o.x = (o.x + acc.x) * s; o.y = (o.y + acc.y) * s;
      o.z = (o.z + acc.z) * s; o.w = (o.w + acc.w) * s;
      *(float4*)(orow + c4) = o;
    }
  }
}

// ---------------- fallback (R1 atomic path) ----------------

__global__ __launch_bounds__(256) void atomic_scatter_kernel(
    const float* __restrict__ src, float* __restrict__ dst,
    const int* __restrict__ u_idx, const int* __restrict__ i_idx,
    const float* __restrict__ w) {
  long long tid = (long long)blockIdx.x * blockDim.x + threadIdx.x;
  int edge = (int)(tid >> 4);
  if (edge >= N_EDGES) return;
  int c = ((int)tid & 15) * 4;
  int ui = u_idx[edge], ii = i_idx[edge];
  float we = w[edge];
  float4 itv = *(const float4*)(src + (long long)ii * CH + c);
  float4 uv  = *(const float4*)(src + ITEM_ELEMS + (long long)ui * CH + c);
  float* ud = dst + ITEM_ELEMS + (long long)ui * CH + c;
  float* id = dst + (long long)ii * CH + c;
  unsafeAtomicAdd(ud + 0, we * itv.x);
  unsafeAtomicAdd(ud + 1, we * itv.y);
  unsafeAtomicAdd(ud + 2, we * itv.z);
  unsafeAtomicAdd(ud + 3, we * itv.w);
  unsafeAtomicAdd(id + 0, we * uv.x);
  unsafeAtomicAdd(id + 1, we * uv.y);
  unsafeAtomicAdd(id + 2, we * uv.z);
  unsafeAtomicAdd(id + 3, we * uv.w);
}

__global__ __launch_bounds__(256) void add_scale_kernel(
    float* __restrict__ acc, const float* __restrict__ add, float s, long long n4) {
  long long i = (long long)blockIdx.x * blockDim.x + threadIdx.x;
  if (i >= n4) return;
  float4 a = ((const float4*)acc)[i];
  float4 b = ((const float4*)add)[i];
  a.x = (a.x + b.x) * s;
  a.y = (a.y + b.y) * s;
  a.z = (a.z + b.z) * s;
  a.w = (a.w + b.w) * s;
  ((float4*)acc)[i] = a;
}

extern "C" void kernel_launch(void* const* d_in, const int* in_sizes, int n_in,
                              void* d_out, int out_size, void* d_ws, size_t ws_size,
                              hipStream_t stream) {
  const float* user_emb = (const float*)d_in[1];
  const float* item_emb = (const float*)d_in[2];
  const int*   edges    = (const int*)d_in[3];
  const int*   u_idx    = edges;            // row 0
  const int*   i_idx    = edges + N_EDGES;  // row 1
  const float* w        = (const float*)d_in[4];

  float* out = (float*)d_out;  // [item_acc | user_acc]

  // workspace layout (4B units)
  float* buf_a   = (float*)d_ws;                 // TOT_ELEMS
  float* buf_b   = buf_a + TOT_ELEMS;            // TOT_ELEMS
  int2*  csr     = (int2*)(buf_b + TOT_ELEMS);   // NDIR int2
  int*   counts  = (int*)(csr + NDIR);           // NROWS
  int*   row_ptr = counts + NROWS;               // NROWS + 1
  int*   cursor  = row_ptr + NROWS + 1;          // NROWS
  int*   blksums = cursor + NROWS;               // 1024
  const size_t needed =
      ((size_t)2 * TOT_ELEMS + 2 * (size_t)NDIR + 3 * (size_t)NROWS + 1 + 1024) * 4;

  // transient aliases (dead before their hosts are written):
  //   seg     aliases buf_a (gather L1 writes buf_a AFTER scatter_fine)
  //   blkwin/segoff/blksums2 alias buf_b (gather L2 writes buf_b later)
  int2* seg      = (int2*)buf_a;                 // NDIR int2 = 32MB <= 38.4MB
  int*  blkwin   = (int*)buf_b;                  // NW16
  int*  segoff   = blkwin + NW16;                // NW16
  int*  blksums2 = segoff + NW16;                // 1024

  if (ws_size >= needed) {
    // ---- CSR build ----
    hipMemsetAsync(counts, 0, (size_t)NROWS * sizeof(int), stream);
    hist_kernel<<<QBLK, 256, 0, stream>>>(u_idx, i_idx, counts, blkwin);
    // row_ptr scan
    const int nblocksA = (NROWS + 255) / 256;  // 587 <= 1024
    scanA_kernel<<<nblocksA, 256, 0, stream>>>(counts, row_ptr, blksums, NROWS);
    scanB_kernel<<<1, 1024, 0, stream>>>(blksums, nblocksA);
    scanC_kernel<<<nblocksA, 256, 0, stream>>>(row_ptr, blksums, cursor, NROWS);
    // segment-offset scan over (win, wave) counts
    const int nblocksW = (NW16 + 255) / 256;   // 489 <= 1024
    scanA_kernel<<<nblocksW, 256, 0, stream>>>(blkwin, segoff, blksums2, NW16);
    scanB_kernel<<<1, 1024, 0, stream>>>(blksums2, nblocksW);
    winscanC_kernel<<<nblocksW, 256, 0, stream>>>(segoff, blksums2, NW16);
    // binned compaction (coalesced) then L2-windowed fine scatter
    seg_write<<<QBLK, 256, 0, stream>>>(u_idx, i_idx, w, segoff, seg);
    scatter_fine<<<8 * FBLKS, 256, 0, stream>>>(seg, segoff, cursor, csr, 0);
    scatter_fine<<<8 * FBLKS, 256, 0, stream>>>(seg, segoff, cursor, csr, 1);

    // ---- layers (gather + fused residual) ----
    const int gather_blocks = (NROWS + 3) / 4;  // 4 rows (waves) per block
    // L1: gather from input tables; out = emb + l1; buf_a = l1
    gather_fused<0><<<gather_blocks, 256, 0, stream>>>(
        item_emb, user_emb, buf_a, out, csr, row_ptr);
    // L2: gather from buf_a; out += l2; buf_b = l2
    gather_fused<1><<<gather_blocks, 256, 0, stream>>>(
        buf_a, buf_a + ITEM_ELEMS, buf_b, out, csr, row_ptr);
    // L3: gather from buf_b; out = (out + l3) * 0.25
    gather_fused<2><<<gather_blocks, 256, 0, stream>>>(
        buf_b, buf_b + ITEM_ELEMS, nullptr, out, csr, row_ptr);
  } else {
    // ---- fallback: R1 atomic scatter ----
    const size_t item_bytes = (size_t)ITEM_ELEMS * sizeof(float);
    const size_t user_bytes = (size_t)USER_ELEMS * sizeof(float);
    hipMemcpyAsync(buf_a,              item_emb, item_bytes, hipMemcpyDeviceToDevice, stream);
    hipMemcpyAsync(buf_a + ITEM_ELEMS, user_emb, user_bytes, hipMemcpyDeviceToDevice, stream);
    hipMemcpyAsync(out,                item_emb, item_bytes, hipMemcpyDeviceToDevice, stream);
    hipMemcpyAsync(out + ITEM_ELEMS,   user_emb, user_bytes, hipMemcpyDeviceToDevice, stream);
    const long long st = (long long)N_EDGES * 16;
    const int sb = (int)((st + 255) / 256);
    const long long n4 = TOT_ELEMS / 4;
    const int add_blocks = (int)((n4 + 255) / 256);
    float* src = buf_a;
    float* dst = buf_b;
    for (int l = 0; l < LAYERS; ++l) {
      hipMemsetAsync(dst, 0, (size_t)TOT_ELEMS * sizeof(float), stream);
      atomic_scatter_kernel<<<sb, 256, 0, stream>>>(src, dst, u_idx, i_idx, w);
      const float s = (l == LAYERS - 1) ? (1.0f / (LAYERS + 1)) : 1.0f;
      add_scale_kernel<<<add_blocks, 256, 0, stream>>>(out, dst, s, n4);
      float* t = src; src = dst; dst = t;
    }
  }
}

// Round 3
// 767.603 us; speedup vs baseline: 1.1342x; 1.1342x over previous
//
#include <hip/hip_runtime.h>

// AttnHGCN.forward_ui — 3-layer bipartite LightGCN-style propagation.
// R8: eliminate ALL device-scope atomics from the CSR build. R7 counters
//     showed hist_kernel = 167us with WRITE_SIZE 125.6MB = 4M atomics x
//     ~32B fabric transactions: device atomics bypass the per-XCD L2 and
//     run at ~24G/s. hist (4M) + scatter_fine cursors (4M) = ~330us of
//     atomic-bound time.
//       bincnt   : per-(win,wave) membership counts via shfl only.
//       scans    : segoff over 32x7816 counts (977 blocks <= 1024).
//       seg_write: compact ends into 32 window segments (coalesced, no
//                  atomics; entries packed (dstLow<<17 | src, wbits)).
//       win_sort : ONE 1024-thread WG per window: LDS hist (4688x4B) ->
//                  block scan -> row_ptr (coalesced) -> LDS-cursor
//                  placement into the window's 1MB CSR range. LDS atomics
//                  only; single-writer window = partial lines merge in one
//                  XCD L2.
//     Gathers unchanged (measured-best R5 form).

constexpr int N_USERS = 100000;
constexpr int N_ITEMS = 50000;
constexpr int CH      = 64;
constexpr int N_EDGES = 2000000;
constexpr int LAYERS  = 3;
constexpr int NROWS   = N_USERS + N_ITEMS;          // 150000 combined dest rows
constexpr int NDIR    = 2 * N_EDGES;                // 4M directed edges

constexpr int QEDGES  = N_EDGES / 4;                // 500000 int4 edge-quads
constexpr int QBLK    = (QEDGES + 255) / 256;       // 1954 blocks over quads
constexpr int NWV     = QBLK * 4;                   // 7816 waves over quads

constexpr int WIN     = 32;                         // row windows
constexpr int WROWSW  = (NROWS + WIN - 1) / WIN;    // 4688 rows per window
constexpr int NWQ     = WIN * NWV;                  // 250112 (win,wave) counts

constexpr long long ITEM_ELEMS = (long long)N_ITEMS * CH;  // 3,200,000
constexpr long long USER_ELEMS = (long long)N_USERS * CH;  // 6,400,000
constexpr long long TOT_ELEMS  = ITEM_ELEMS + USER_ELEMS;  // 9,600,000

typedef int   v4i __attribute__((ext_vector_type(4)));
typedef float v4f __attribute__((ext_vector_type(4)));

// ---------------- CSR build (zero device atomics) ----------------

// Per-(window, wave) end counts via shfl reduction. No early return: all
// lanes participate in the shfl reductions.
__global__ __launch_bounds__(256) void bincnt_kernel(
    const int* __restrict__ u_idx, const int* __restrict__ i_idx,
    int* __restrict__ blkwin) {
  int q = blockIdx.x * 256 + threadIdx.x;
  bool valid = (q < QEDGES);
  v4i u  = {0, 0, 0, 0};
  v4i it = {0, 0, 0, 0};
  if (valid) {
    u  = *(const v4i*)(u_idx + 4 * (long long)q);
    it = *(const v4i*)(i_idx + 4 * (long long)q);
  }
  int rows[8];
  if (valid) {
    rows[0] = u.x; rows[1] = u.y; rows[2] = u.z; rows[3] = u.w;
    rows[4] = N_USERS + it.x; rows[5] = N_USERS + it.y;
    rows[6] = N_USERS + it.z; rows[7] = N_USERS + it.w;
  } else {
#pragma unroll
    for (int k = 0; k < 8; ++k) rows[k] = -1;
  }
  int lane = threadIdx.x & 63;
  int gw   = blockIdx.x * 4 + (threadIdx.x >> 6);
#pragma unroll
  for (int win = 0; win < WIN; ++win) {
    const int wlo = win * WROWSW;
    int c = 0;
#pragma unroll
    for (int k = 0; k < 8; ++k)
      c += ((unsigned)(rows[k] - wlo) < (unsigned)WROWSW) ? 1 : 0;
#pragma unroll
    for (int d = 1; d < 64; d <<= 1) c += __shfl_xor(c, d, 64);
    if (lane == 0) blkwin[win * NWV + gw] = c;
  }
}

// per-256-block exclusive scan; block sums out (generic)
__global__ __launch_bounds__(256) void scanA_kernel(
    const int* __restrict__ in, int* __restrict__ out,
    int* __restrict__ blksums, int n) {
  __shared__ int sh[256];
  int t = threadIdx.x;
  int i = blockIdx.x * 256 + t;
  int v = (i < n) ? in[i] : 0;
  int x = v;
  sh[t] = x; __syncthreads();
  for (int d = 1; d < 256; d <<= 1) {
    int add = (t >= d) ? sh[t - d] : 0;
    __syncthreads();
    x += add; sh[t] = x;
    __syncthreads();
  }
  if (i < n) out[i] = x - v;  // exclusive within block
  if (t == 255) blksums[blockIdx.x] = x;
}

// single-block exclusive scan of block sums (n2 <= 1024)
__global__ __launch_bounds__(1024) void scanB_kernel(int* __restrict__ blksums, int n2) {
  __shared__ int sh[1024];
  int t = threadIdx.x;
  int v = (t < n2) ? blksums[t] : 0;
  int x = v;
  sh[t] = x; __syncthreads();
  for (int d = 1; d < 1024; d <<= 1) {
    int add = (t >= d) ? sh[t - d] : 0;
    __syncthreads();
    x += add; sh[t] = x;
    __syncthreads();
  }
  if (t < n2) blksums[t] = x - v;  // exclusive
}

// add block offsets (segment-offset variant)
__global__ __launch_bounds__(256) void winscanC_kernel(
    int* __restrict__ out, const int* __restrict__ blksums, int n) {
  int i = blockIdx.x * 256 + threadIdx.x;
  if (i < n) out[i] += blksums[i >> 8];
}

// Compact every directed end into its window's segment at a deterministic,
// wave-scanned position. All stores coalesced; zero atomics.
// Entry packing: x = (dstLow<<17) | src  (dstLow<4688 fits 13b, src<2^17),
//                y = float bits of w.
__global__ __launch_bounds__(256) void seg_write(
    const int* __restrict__ u_idx, const int* __restrict__ i_idx,
    const float* __restrict__ wv, const int* __restrict__ segoff,
    int2* __restrict__ seg) {
  int q = blockIdx.x * 256 + threadIdx.x;
  bool valid = (q < QEDGES);
  v4i u  = {0, 0, 0, 0};
  v4i it = {0, 0, 0, 0};
  v4f w  = {0.f, 0.f, 0.f, 0.f};
  if (valid) {
    u  = *(const v4i*)(u_idx + 4 * (long long)q);
    it = *(const v4i*)(i_idx + 4 * (long long)q);
    w  = *(const v4f*)(wv + 4 * (long long)q);
  }
  int rows[8], srcs[8], wbits[8];
  if (valid) {
    rows[0] = u.x; rows[1] = u.y; rows[2] = u.z; rows[3] = u.w;
    srcs[0] = it.x; srcs[1] = it.y; srcs[2] = it.z; srcs[3] = it.w;
    rows[4] = N_USERS + it.x; rows[5] = N_USERS + it.y;
    rows[6] = N_USERS + it.z; rows[7] = N_USERS + it.w;
    srcs[4] = u.x; srcs[5] = u.y; srcs[6] = u.z; srcs[7] = u.w;
    wbits[0] = __float_as_int(w.x); wbits[1] = __float_as_int(w.y);
    wbits[2] = __float_as_int(w.z); wbits[3] = __float_as_int(w.w);
    wbits[4] = wbits[0]; wbits[5] = wbits[1];
    wbits[6] = wbits[2]; wbits[7] = wbits[3];
  } else {
#pragma unroll
    for (int k = 0; k < 8; ++k) { rows[k] = -1; srcs[k] = 0; wbits[k] = 0; }
  }
  int lane = threadIdx.x & 63;
  int gw   = blockIdx.x * 4 + (threadIdx.x >> 6);
#pragma unroll
  for (int win = 0; win < WIN; ++win) {
    const int wlo = win * WROWSW;
    int c = 0;
#pragma unroll
    for (int k = 0; k < 8; ++k)
      c += ((unsigned)(rows[k] - wlo) < (unsigned)WROWSW) ? 1 : 0;
    // inclusive wave scan of c
    int x = c;
#pragma unroll
    for (int d = 1; d < 64; d <<= 1) {
      int y = __shfl_up(x, d, 64);
      if (lane >= d) x += y;
    }
    int pos = segoff[win * NWV + gw] + (x - c);  // exclusive prefix
#pragma unroll
    for (int k = 0; k < 8; ++k) {
      int dl = rows[k] - wlo;
      if ((unsigned)dl < (unsigned)WROWSW) {
        seg[pos++] = make_int2((dl << 17) | srcs[k], wbits[k]);
      }
    }
  }
}

// Counting sort of one window's segment into its CSR range.
// One 1024-thread WG per window; LDS hist + LDS cursors; no device atomics.
// Also emits row_ptr (window base + within-window exclusive scan).
__global__ __launch_bounds__(1024) void win_sort(
    const int2* __restrict__ seg, const int* __restrict__ segoff,
    int* __restrict__ row_ptr, int2* __restrict__ csr) {
  __shared__ int hist[WROWSW];   // 4688 * 4B = 18752 B
  __shared__ int aux[1024];
  const int win = blockIdx.x;
  const int wlo = win * WROWSW;
  const int wsz = min(WROWSW, NROWS - wlo);
  const int s0  = segoff[win * NWV];
  const int s1  = (win < WIN - 1) ? segoff[(win + 1) * NWV] : NDIR;
  const int t   = threadIdx.x;

  for (int r = t; r < WROWSW; r += 1024) hist[r] = 0;
  __syncthreads();

  // pass A: LDS histogram of dstLow (4-way unrolled for MLP)
  for (int idx = s0 + t; idx < s1; idx += 4096) {
    int i1 = idx + 1024, i2 = idx + 2048, i3 = idx + 3072;
    int x0 = seg[idx].x;
    int x1 = (i1 < s1) ? seg[i1].x : -1;
    int x2 = (i2 < s1) ? seg[i2].x : -1;
    int x3 = (i3 < s1) ? seg[i3].x : -1;
    atomicAdd(&hist[((unsigned)x0) >> 17], 1);
    if (x1 >= 0) atomicAdd(&hist[((unsigned)x1) >> 17], 1);
    if (x2 >= 0) atomicAdd(&hist[((unsigned)x2) >> 17], 1);
    if (x3 >= 0) atomicAdd(&hist[((unsigned)x3) >> 17], 1);
  }
  __syncthreads();

  // block-wide exclusive scan of hist: 5 rows per thread + aux scan
  constexpr int CPT = (WROWSW + 1023) / 1024;  // 5
  const int base = t * CPT;
  int vals[CPT];
  int s = 0;
#pragma unroll
  for (int k = 0; k < CPT; ++k) {
    int r = base + k;
    vals[k] = (r < WROWSW) ? hist[r] : 0;
    s += vals[k];
  }
  int x = s;
  aux[t] = x; __syncthreads();
  for (int d = 1; d < 1024; d <<= 1) {
    int add = (t >= d) ? aux[t - d] : 0;
    __syncthreads();
    x += add; aux[t] = x;
    __syncthreads();
  }
  int run = x - s;  // exclusive prefix of this thread's chunk
#pragma unroll
  for (int k = 0; k < CPT; ++k) {
    int r = base + k;
    if (r < WROWSW) {
      hist[r] = run;                              // becomes LDS cursor
      if (r < wsz) row_ptr[wlo + r] = s0 + run;   // coalesced row_ptr
      run += vals[k];
    }
  }
  if (win == WIN - 1 && t == 0) row_ptr[NROWS] = NDIR;
  __syncthreads();

  // pass B: placement via LDS cursors (4-way unrolled)
  for (int idx = s0 + t; idx < s1; idx += 4096) {
    int i1 = idx + 1024, i2 = idx + 2048, i3 = idx + 3072;
    int2 e0 = seg[idx];
    int2 e1 = (i1 < s1) ? seg[i1] : make_int2(-1, 0);
    int2 e2 = (i2 < s1) ? seg[i2] : make_int2(-1, 0);
    int2 e3 = (i3 < s1) ? seg[i3] : make_int2(-1, 0);
    {
      int p = atomicAdd(&hist[((unsigned)e0.x) >> 17], 1);
      csr[s0 + p] = make_int2(e0.x & 0x1FFFF, e0.y);
    }
    if (e1.x >= 0) {
      int p = atomicAdd(&hist[((unsigned)e1.x) >> 17], 1);
      csr[s0 + p] = make_int2(e1.x & 0x1FFFF, e1.y);
    }
    if (e2.x >= 0) {
      int p = atomicAdd(&hist[((unsigned)e2.x) >> 17], 1);
      csr[s0 + p] = make_int2(e2.x & 0x1FFFF, e2.y);
    }
    if (e3.x >= 0) {
      int p = atomicAdd(&hist[((unsigned)e3.x) >> 17], 1);
      csr[s0 + p] = make_int2(e3.x & 0x1FFFF, e3.y);
    }
  }
}

// ---------------- per-layer fused gather (R5 form) ----------------
// One wave per destination row; lane = slot(2b) x chan16(4b); adjacency loop
// unrolled x2 -> 8 edges (8x256B gathers) in flight per wave; butterfly-
// reduce slots. Epilogue fuses residual accumulation:
//   MODE 0 (layer 1):   dst = acc;  out = emb + acc
//   MODE 1 (mid layer): dst = acc;  out += acc
//   MODE 2 (last):                  out = (out + acc) * 1/(LAYERS+1)
template <int MODE>
__global__ __launch_bounds__(256) void gather_fused(
    const float* __restrict__ it_tab,  // gather-source item table
    const float* __restrict__ u_tab,   // gather-source user table
    float* __restrict__ dst,           // [it|u] layer output (MODE<2)
    float* __restrict__ out,           // [item_acc | user_acc]
    const int2* __restrict__ csr,
    const int* __restrict__ row_ptr) {
  int row = blockIdx.x * 4 + (threadIdx.x >> 6);
  if (row >= NROWS) return;
  int lane = threadIdx.x & 63;
  int slot = lane >> 4;          // 0..3
  int c4   = (lane & 15) * 4;    // channel offset 0..60

  const float* gtab;             // opposite-side table to gather from
  const float* erow = nullptr;   // dest-side input-emb row (MODE 0)
  float* drow = nullptr;
  float* orow;
  if (row < N_USERS) {
    gtab = it_tab;
    orow = out + ITEM_ELEMS + (long long)row * CH;
    if (MODE < 2)  drow = dst + ITEM_ELEMS + (long long)row * CH;
    if (MODE == 0) erow = u_tab + (long long)row * CH;  // u_tab==user_emb here
  } else {
    int r = row - N_USERS;
    gtab = u_tab;
    orow = out + (long long)r * CH;
    if (MODE < 2)  drow = dst + (long long)r * CH;
    if (MODE == 0) erow = it_tab + (long long)r * CH;   // it_tab==item_emb here
  }

  int beg = row_ptr[row], end = row_ptr[row + 1];
  float4 acc = make_float4(0.f, 0.f, 0.f, 0.f);
  int j = beg + slot;
  // unrolled x2: two independent (csr, row) load pairs in flight
  for (; j + 4 < end; j += 8) {
    int2  e0 = csr[j];
    int2  e1 = csr[j + 4];
    float4 v0 = *(const float4*)(gtab + (long long)e0.x * CH + c4);
    float4 v1 = *(const float4*)(gtab + (long long)e1.x * CH + c4);
    float w0 = __int_as_float(e0.y);
    float w1 = __int_as_float(e1.y);
    acc.x += w0 * v0.x; acc.y += w0 * v0.y;
    acc.z += w0 * v0.z; acc.w += w0 * v0.w;
    acc.x += w1 * v1.x; acc.y += w1 * v1.y;
    acc.z += w1 * v1.z; acc.w += w1 * v1.w;
  }
  if (j < end) {
    int2  e  = csr[j];
    float we = __int_as_float(e.y);
    float4 v = *(const float4*)(gtab + (long long)e.x * CH + c4);
    acc.x += we * v.x; acc.y += we * v.y;
    acc.z += we * v.z; acc.w += we * v.w;
  }
  for (int off = 16; off < 64; off <<= 1) {
    acc.x += __shfl_xor(acc.x, off, 64);
    acc.y += __shfl_xor(acc.y, off, 64);
    acc.z += __shfl_xor(acc.z, off, 64);
    acc.w += __shfl_xor(acc.w, off, 64);
  }
  if (slot == 0) {
    if (MODE == 0) {
      float4 e4 = *(const float4*)(erow + c4);
      *(float4*)(drow + c4) = acc;
      e4.x += acc.x; e4.y += acc.y; e4.z += acc.z; e4.w += acc.w;
      *(float4*)(orow + c4) = e4;
    } else if (MODE == 1) {
      float4 o = *(const float4*)(orow + c4);
      *(float4*)(drow + c4) = acc;
      o.x += acc.x; o.y += acc.y; o.z += acc.z; o.w += acc.w;
      *(float4*)(orow + c4) = o;
    } else {
      const float s = 1.0f / (LAYERS + 1);
      float4 o = *(const float4*)(orow + c4);
      o.x = (o.x + acc.x) * s; o.y = (o.y + acc.y) * s;
      o.z = (o.z + acc.z) * s; o.w = (o.w + acc.w) * s;
      *(float4*)(orow + c4) = o;
    }
  }
}

// ---------------- fallback (R1 atomic path) ----------------

__global__ __launch_bounds__(256) void atomic_scatter_kernel(
    const float* __restrict__ src, float* __restrict__ dst,
    const int* __restrict__ u_idx, const int* __restrict__ i_idx,
    const float* __restrict__ w) {
  long long tid = (long long)blockIdx.x * blockDim.x + threadIdx.x;
  int edge = (int)(tid >> 4);
  if (edge >= N_EDGES) return;
  int c = ((int)tid & 15) * 4;
  int ui = u_idx[edge], ii = i_idx[edge];
  float we = w[edge];
  float4 itv = *(const float4*)(src + (long long)ii * CH + c);
  float4 uv  = *(const float4*)(src + ITEM_ELEMS + (long long)ui * CH + c);
  float* ud = dst + ITEM_ELEMS + (long long)ui * CH + c;
  float* id = dst + (long long)ii * CH + c;
  unsafeAtomicAdd(ud + 0, we * itv.x);
  unsafeAtomicAdd(ud + 1, we * itv.y);
  unsafeAtomicAdd(ud + 2, we * itv.z);
  unsafeAtomicAdd(ud + 3, we * itv.w);
  unsafeAtomicAdd(id + 0, we * uv.x);
  unsafeAtomicAdd(id + 1, we * uv.y);
  unsafeAtomicAdd(id + 2, we * uv.z);
  unsafeAtomicAdd(id + 3, we * uv.w);
}

__global__ __launch_bounds__(256) void add_scale_kernel(
    float* __restrict__ acc, const float* __restrict__ add, float s, long long n4) {
  long long i = (long long)blockIdx.x * blockDim.x + threadIdx.x;
  if (i >= n4) return;
  float4 a = ((const float4*)acc)[i];
  float4 b = ((const float4*)add)[i];
  a.x = (a.x + b.x) * s;
  a.y = (a.y + b.y) * s;
  a.z = (a.z + b.z) * s;
  a.w = (a.w + b.w) * s;
  ((float4*)acc)[i] = a;
}

extern "C" void kernel_launch(void* const* d_in, const int* in_sizes, int n_in,
                              void* d_out, int out_size, void* d_ws, size_t ws_size,
                              hipStream_t stream) {
  const float* user_emb = (const float*)d_in[1];
  const float* item_emb = (const float*)d_in[2];
  const int*   edges    = (const int*)d_in[3];
  const int*   u_idx    = edges;            // row 0
  const int*   i_idx    = edges + N_EDGES;  // row 1
  const float* w        = (const float*)d_in[4];

  float* out = (float*)d_out;  // [item_acc | user_acc]

  // workspace layout (4B units) — offsets kept identical to R7
  float* buf_a   = (float*)d_ws;                 // TOT_ELEMS
  float* buf_b   = buf_a + TOT_ELEMS;            // TOT_ELEMS
  int2*  csr     = (int2*)(buf_b + TOT_ELEMS);   // NDIR int2
  int*   ibase   = (int*)(csr + NDIR);           // (was counts) NROWS
  int*   row_ptr = ibase + NROWS;                // NROWS + 1
  const size_t needed =
      ((size_t)2 * TOT_ELEMS + 2 * (size_t)NDIR + 3 * (size_t)NROWS + 1 + 1024) * 4;

  // transient aliases (dead before their hosts are written):
  //   seg     aliases buf_a (gather L1 writes buf_a AFTER win_sort)
  //   blkwin/segoff/blksums2 alias buf_b (gather L2 writes buf_b later)
  int2* seg      = (int2*)buf_a;                 // NDIR int2 = 32MB <= 38.4MB
  int*  blkwin   = (int*)buf_b;                  // NWQ (250112)
  int*  segoff   = blkwin + NWQ;                 // NWQ
  int*  blksums2 = segoff + NWQ;                 // 1024

  if (ws_size >= needed) {
    // ---- CSR build (zero device atomics) ----
    bincnt_kernel<<<QBLK, 256, 0, stream>>>(u_idx, i_idx, blkwin);
    const int nblocksW = (NWQ + 255) / 256;   // 977 <= 1024
    scanA_kernel<<<nblocksW, 256, 0, stream>>>(blkwin, segoff, blksums2, NWQ);
    scanB_kernel<<<1, 1024, 0, stream>>>(blksums2, nblocksW);
    winscanC_kernel<<<nblocksW, 256, 0, stream>>>(segoff, blksums2, NWQ);
    seg_write<<<QBLK, 256, 0, stream>>>(u_idx, i_idx, w, segoff, seg);
    win_sort<<<WIN, 1024, 0, stream>>>(seg, segoff, row_ptr, csr);

    // ---- layers (gather + fused residual) ----
    const int gather_blocks = (NROWS + 3) / 4;  // 4 rows (waves) per block
    // L1: gather from input tables; out = emb + l1; buf_a = l1
    gather_fused<0><<<gather_blocks, 256, 0, stream>>>(
        item_emb, user_emb, buf_a, out, csr, row_ptr);
    // L2: gather from buf_a; out += l2; buf_b = l2
    gather_fused<1><<<gather_blocks, 256, 0, stream>>>(
        buf_a, buf_a + ITEM_ELEMS, buf_b, out, csr, row_ptr);
    // L3: gather from buf_b; out = (out + l3) * 0.25
    gather_fused<2><<<gather_blocks, 256, 0, stream>>>(
        buf_b, buf_b + ITEM_ELEMS, nullptr, out, csr, row_ptr);
  } else {
    // ---- fallback: R1 atomic scatter ----
    const size_t item_bytes = (size_t)ITEM_ELEMS * sizeof(float);
    const size_t user_bytes = (size_t)USER_ELEMS * sizeof(float);
    hipMemcpyAsync(buf_a,              item_emb, item_bytes, hipMemcpyDeviceToDevice, stream);
    hipMemcpyAsync(buf_a + ITEM_ELEMS, user_emb, user_bytes, hipMemcpyDeviceToDevice, stream);
    hipMemcpyAsync(out,                item_emb, item_bytes, hipMemcpyDeviceToDevice, stream);
    hipMemcpyAsync(out + ITEM_ELEMS,   user_emb, user_bytes, hipMemcpyDeviceToDevice, stream);
    const long long st = (long long)N_EDGES * 16;
    const int sb = (int)((st + 255) / 256);
    const long long n4 = TOT_ELEMS / 4;
    const int add_blocks = (int)((n4 + 255) / 256);
    float* src = buf_a;
    float* dst = buf_b;
    for (int l = 0; l < LAYERS; ++l) {
      hipMemsetAsync(dst, 0, (size_t)TOT_ELEMS * sizeof(float), stream);
      atomic_scatter_kernel<<<sb, 256, 0, stream>>>(src, dst, u_idx, i_idx, w);
      const float s = (l == LAYERS - 1) ? (1.0f / (LAYERS + 1)) : 1.0f;
      add_scale_kernel<<<add_blocks, 256, 0, stream>>>(out, dst, s, n4);
      float* t = src; src = dst; dst = t;
    }
  }
}

// Round 4
// 633.401 us; speedup vs baseline: 1.3746x; 1.2119x over previous
//
#include <hip/hip_runtime.h>

// AttnHGCN.forward_ui — 3-layer bipartite LightGCN-style propagation.
// R9: full-chip counting sort. R8's win_sort ran at OccupancyPercent=3%
//     (one WG per window, 32 WGs on 256 CUs) = 210us latency-bound.
//     Split each window into 16 segment-chunks with deterministic
//     per-(row,chunk) bases:
//       win_hist  : 512 WGs (32win x 16chunk) LDS-histogram their chunk ->
//                   hist2[win][chunk][row] (coalesced dump).
//       chunk_scan: per row-slot, exclusive-prefix the 16 chunk counts in
//                   place; slot total -> cnt_slot. Windows are contiguous
//                   equal-size rows => global scan of cnt_slot == row_ptr.
//       win_place : 512 WGs re-read their chunk, place via LDS cursors
//                   (row_ptr + chunk prefix). XCD-pinned: win=blockIdx&31
//                   => blockIdx%8 = win%8, all 16 chunks of a window store
//                   through ONE XCD L2 (partial-line merge preserved).
//     Zero device-scope atomics anywhere in the build (R8 lesson: device
//     atomics bypass L2, ~24G/s, 32B fabric transactions each).
//     Gathers unchanged (measured-best R5 form).

constexpr int N_USERS = 100000;
constexpr int N_ITEMS = 50000;
constexpr int CH      = 64;
constexpr int N_EDGES = 2000000;
constexpr int LAYERS  = 3;
constexpr int NROWS   = N_USERS + N_ITEMS;          // 150000 combined dest rows
constexpr int NDIR    = 2 * N_EDGES;                // 4M directed edges

constexpr int QEDGES  = N_EDGES / 4;                // 500000 int4 edge-quads
constexpr int QBLK    = (QEDGES + 255) / 256;       // 1954 blocks over quads
constexpr int NWV     = QBLK * 4;                   // 7816 waves over quads

constexpr int WIN     = 32;                         // row windows
constexpr int WROWSW  = (NROWS + WIN - 1) / WIN;    // 4688 rows per window
constexpr int NWQ     = WIN * NWV;                  // 250112 (win,wave) counts

constexpr int CHUNKS  = 16;                         // segment chunks per window
constexpr int SORTWG  = WIN * CHUNKS;               // 512 sort workgroups
constexpr int NSLOT   = WIN * WROWSW;               // 150016 row slots
constexpr int H2SZ    = WIN * CHUNKS * WROWSW;      // 2,400,256 hist2 ints

constexpr long long ITEM_ELEMS = (long long)N_ITEMS * CH;  // 3,200,000
constexpr long long USER_ELEMS = (long long)N_USERS * CH;  // 6,400,000
constexpr long long TOT_ELEMS  = ITEM_ELEMS + USER_ELEMS;  // 9,600,000

typedef int   v4i __attribute__((ext_vector_type(4)));
typedef float v4f __attribute__((ext_vector_type(4)));

// ---------------- CSR build (zero device atomics) ----------------

// Per-(window, wave) end counts via shfl reduction. No early return: all
// lanes participate in the shfl reductions.
__global__ __launch_bounds__(256) void bincnt_kernel(
    const int* __restrict__ u_idx, const int* __restrict__ i_idx,
    int* __restrict__ blkwin) {
  int q = blockIdx.x * 256 + threadIdx.x;
  bool valid = (q < QEDGES);
  v4i u  = {0, 0, 0, 0};
  v4i it = {0, 0, 0, 0};
  if (valid) {
    u  = *(const v4i*)(u_idx + 4 * (long long)q);
    it = *(const v4i*)(i_idx + 4 * (long long)q);
  }
  int rows[8];
  if (valid) {
    rows[0] = u.x; rows[1] = u.y; rows[2] = u.z; rows[3] = u.w;
    rows[4] = N_USERS + it.x; rows[5] = N_USERS + it.y;
    rows[6] = N_USERS + it.z; rows[7] = N_USERS + it.w;
  } else {
#pragma unroll
    for (int k = 0; k < 8; ++k) rows[k] = -1;
  }
  int lane = threadIdx.x & 63;
  int gw   = blockIdx.x * 4 + (threadIdx.x >> 6);
#pragma unroll
  for (int win = 0; win < WIN; ++win) {
    const int wlo = win * WROWSW;
    int c = 0;
#pragma unroll
    for (int k = 0; k < 8; ++k)
      c += ((unsigned)(rows[k] - wlo) < (unsigned)WROWSW) ? 1 : 0;
#pragma unroll
    for (int d = 1; d < 64; d <<= 1) c += __shfl_xor(c, d, 64);
    if (lane == 0) blkwin[win * NWV + gw] = c;
  }
}

// per-256-block exclusive scan; block sums out (generic; in==out ok)
__global__ __launch_bounds__(256) void scanA_kernel(
    const int* __restrict__ in, int* __restrict__ out,
    int* __restrict__ blksums, int n) {
  __shared__ int sh[256];
  int t = threadIdx.x;
  int i = blockIdx.x * 256 + t;
  int v = (i < n) ? in[i] : 0;
  int x = v;
  sh[t] = x; __syncthreads();
  for (int d = 1; d < 256; d <<= 1) {
    int add = (t >= d) ? sh[t - d] : 0;
    __syncthreads();
    x += add; sh[t] = x;
    __syncthreads();
  }
  if (i < n) out[i] = x - v;  // exclusive within block
  if (t == 255) blksums[blockIdx.x] = x;
}

// single-block exclusive scan of block sums (n2 <= 1024)
__global__ __launch_bounds__(1024) void scanB_kernel(int* __restrict__ blksums, int n2) {
  __shared__ int sh[1024];
  int t = threadIdx.x;
  int v = (t < n2) ? blksums[t] : 0;
  int x = v;
  sh[t] = x; __syncthreads();
  for (int d = 1; d < 1024; d <<= 1) {
    int add = (t >= d) ? sh[t - d] : 0;
    __syncthreads();
    x += add; sh[t] = x;
    __syncthreads();
  }
  if (t < n2) blksums[t] = x - v;  // exclusive
}

// add block offsets (segment-offset variant)
__global__ __launch_bounds__(256) void winscanC_kernel(
    int* __restrict__ out, const int* __restrict__ blksums, int n) {
  int i = blockIdx.x * 256 + threadIdx.x;
  if (i < n) out[i] += blksums[i >> 8];
}

// Compact every directed end into its window's segment at a deterministic,
// wave-scanned position. All stores coalesced; zero atomics.
// Entry packing: x = (dstLow<<17) | src  (dstLow<4688 fits 13b, src<2^17),
//                y = float bits of w.
__global__ __launch_bounds__(256) void seg_write(
    const int* __restrict__ u_idx, const int* __restrict__ i_idx,
    const float* __restrict__ wv, const int* __restrict__ segoff,
    int2* __restrict__ seg) {
  int q = blockIdx.x * 256 + threadIdx.x;
  bool valid = (q < QEDGES);
  v4i u  = {0, 0, 0, 0};
  v4i it = {0, 0, 0, 0};
  v4f w  = {0.f, 0.f, 0.f, 0.f};
  if (valid) {
    u  = *(const v4i*)(u_idx + 4 * (long long)q);
    it = *(const v4i*)(i_idx + 4 * (long long)q);
    w  = *(const v4f*)(wv + 4 * (long long)q);
  }
  int rows[8], srcs[8], wbits[8];
  if (valid) {
    rows[0] = u.x; rows[1] = u.y; rows[2] = u.z; rows[3] = u.w;
    srcs[0] = it.x; srcs[1] = it.y; srcs[2] = it.z; srcs[3] = it.w;
    rows[4] = N_USERS + it.x; rows[5] = N_USERS + it.y;
    rows[6] = N_USERS + it.z; rows[7] = N_USERS + it.w;
    srcs[4] = u.x; srcs[5] = u.y; srcs[6] = u.z; srcs[7] = u.w;
    wbits[0] = __float_as_int(w.x); wbits[1] = __float_as_int(w.y);
    wbits[2] = __float_as_int(w.z); wbits[3] = __float_as_int(w.w);
    wbits[4] = wbits[0]; wbits[5] = wbits[1];
    wbits[6] = wbits[2]; wbits[7] = wbits[3];
  } else {
#pragma unroll
    for (int k = 0; k < 8; ++k) { rows[k] = -1; srcs[k] = 0; wbits[k] = 0; }
  }
  int lane = threadIdx.x & 63;
  int gw   = blockIdx.x * 4 + (threadIdx.x >> 6);
#pragma unroll
  for (int win = 0; win < WIN; ++win) {
    const int wlo = win * WROWSW;
    int c = 0;
#pragma unroll
    for (int k = 0; k < 8; ++k)
      c += ((unsigned)(rows[k] - wlo) < (unsigned)WROWSW) ? 1 : 0;
    // inclusive wave scan of c
    int x = c;
#pragma unroll
    for (int d = 1; d < 64; d <<= 1) {
      int y = __shfl_up(x, d, 64);
      if (lane >= d) x += y;
    }
    int pos = segoff[win * NWV + gw] + (x - c);  // exclusive prefix
#pragma unroll
    for (int k = 0; k < 8; ++k) {
      int dl = rows[k] - wlo;
      if ((unsigned)dl < (unsigned)WROWSW) {
        seg[pos++] = make_int2((dl << 17) | srcs[k], wbits[k]);
      }
    }
  }
}

// Phase 1: per-(window,chunk) LDS histogram of dstLow -> hist2 dump.
// win = blockIdx&31 so blockIdx%8 = win%8 (XCD pin, matters for phase 3).
__global__ __launch_bounds__(1024) void win_hist(
    const int2* __restrict__ seg, const int* __restrict__ segoff,
    int* __restrict__ hist2) {
  __shared__ int hist[WROWSW];   // 18752 B
  const int win   = blockIdx.x & 31;
  const int chunk = blockIdx.x >> 5;
  const int s0  = segoff[win * NWV];
  const int s1  = (win < WIN - 1) ? segoff[(win + 1) * NWV] : NDIR;
  const int csz = (s1 - s0 + CHUNKS - 1) / CHUNKS;
  const int c0  = s0 + chunk * csz;
  const int c1  = min(c0 + csz, s1);
  const int t   = threadIdx.x;
  for (int r = t; r < WROWSW; r += 1024) hist[r] = 0;
  __syncthreads();
  for (int idx = c0 + t; idx < c1; idx += 2048) {
    int i1 = idx + 1024;
    int x0 = seg[idx].x;
    int x1 = (i1 < c1) ? seg[i1].x : -1;
    atomicAdd(&hist[((unsigned)x0) >> 17], 1);
    if (x1 >= 0) atomicAdd(&hist[((unsigned)x1) >> 17], 1);
  }
  __syncthreads();
  int* hout = hist2 + (long long)(win * CHUNKS + chunk) * WROWSW;
  for (int r = t; r < WROWSW; r += 1024) hout[r] = hist[r];
}

// Phase 2: per row-slot, exclusive-prefix the CHUNKS counts in place;
// slot total -> cnt_slot. slot index == global row index (equal windows,
// padding slots at the very end).
__global__ __launch_bounds__(256) void chunk_scan(
    int* __restrict__ hist2, int* __restrict__ cnt_slot) {
  int i = blockIdx.x * 256 + threadIdx.x;
  if (i >= NSLOT) return;
  int win = i / WROWSW;
  int dl  = i - win * WROWSW;
  int* h = hist2 + (long long)win * CHUNKS * WROWSW + dl;
  int run = 0;
#pragma unroll
  for (int c = 0; c < CHUNKS; ++c) {
    long long o = (long long)c * WROWSW;
    int v = h[o];
    h[o] = run;
    run += v;
  }
  cnt_slot[i] = run;
}

// finalize row_ptr from the scanned cnt_slot (+ terminator)
__global__ __launch_bounds__(256) void rowptrC_kernel(
    const int* __restrict__ cnt_exc, const int* __restrict__ blksums,
    int* __restrict__ row_ptr) {
  int i = blockIdx.x * 256 + threadIdx.x;
  if (i < NROWS) row_ptr[i] = cnt_exc[i] + blksums[i >> 8];
  if (i == 0) row_ptr[NROWS] = NDIR;
}

// Phase 3: placement. LDS cursor = row_ptr[row] + per-chunk prefix; each
// chunk WG owns a disjoint slice of every row's CSR run -> LDS atomics
// only, positions globally unique. XCD-pinned per window (win = blk&31).
__global__ __launch_bounds__(1024) void win_place(
    const int2* __restrict__ seg, const int* __restrict__ segoff,
    const int* __restrict__ hist2, const int* __restrict__ row_ptr,
    int2* __restrict__ csr) {
  __shared__ int cur[WROWSW];    // 18752 B
  const int win   = blockIdx.x & 31;
  const int chunk = blockIdx.x >> 5;
  const int wlo = win * WROWSW;
  const int wsz = min(WROWSW, NROWS - wlo);
  const int s0  = segoff[win * NWV];
  const int s1  = (win < WIN - 1) ? segoff[(win + 1) * NWV] : NDIR;
  const int csz = (s1 - s0 + CHUNKS - 1) / CHUNKS;
  const int c0  = s0 + chunk * csz;
  const int c1  = min(c0 + csz, s1);
  const int t   = threadIdx.x;
  const int* hin = hist2 + (long long)(win * CHUNKS + chunk) * WROWSW;
  for (int r = t; r < wsz; r += 1024) cur[r] = row_ptr[wlo + r] + hin[r];
  __syncthreads();
  for (int idx = c0 + t; idx < c1; idx += 2048) {
    int i1 = idx + 1024;
    int2 e0 = seg[idx];
    int2 e1 = (i1 < c1) ? seg[i1] : make_int2(-1, 0);
    {
      int p = atomicAdd(&cur[((unsigned)e0.x) >> 17], 1);
      csr[p] = make_int2(e0.x & 0x1FFFF, e0.y);
    }
    if (e1.x >= 0) {
      int p = atomicAdd(&cur[((unsigned)e1.x) >> 17], 1);
      csr[p] = make_int2(e1.x & 0x1FFFF, e1.y);
    }
  }
}

// ---------------- per-layer fused gather (R5 form) ----------------
// One wave per destination row; lane = slot(2b) x chan16(4b); adjacency loop
// unrolled x2 -> 8 edges (8x256B gathers) in flight per wave; butterfly-
// reduce slots. Epilogue fuses residual accumulation:
//   MODE 0 (layer 1):   dst = acc;  out = emb + acc
//   MODE 1 (mid layer): dst = acc;  out += acc
//   MODE 2 (last):                  out = (out + acc) * 1/(LAYERS+1)
template <int MODE>
__global__ __launch_bounds__(256) void gather_fused(
    const float* __restrict__ it_tab,  // gather-source item table
    const float* __restrict__ u_tab,   // gather-source user table
    float* __restrict__ dst,           // [it|u] layer output (MODE<2)
    float* __restrict__ out,           // [item_acc | user_acc]
    const int2* __restrict__ csr,
    const int* __restrict__ row_ptr) {
  int row = blockIdx.x * 4 + (threadIdx.x >> 6);
  if (row >= NROWS) return;
  int lane = threadIdx.x & 63;
  int slot = lane >> 4;          // 0..3
  int c4   = (lane & 15) * 4;    // channel offset 0..60

  const float* gtab;             // opposite-side table to gather from
  const float* erow = nullptr;   // dest-side input-emb row (MODE 0)
  float* drow = nullptr;
  float* orow;
  if (row < N_USERS) {
    gtab = it_tab;
    orow = out + ITEM_ELEMS + (long long)row * CH;
    if (MODE < 2)  drow = dst + ITEM_ELEMS + (long long)row * CH;
    if (MODE == 0) erow = u_tab + (long long)row * CH;  // u_tab==user_emb here
  } else {
    int r = row - N_USERS;
    gtab = u_tab;
    orow = out + (long long)r * CH;
    if (MODE < 2)  drow = dst + (long long)r * CH;
    if (MODE == 0) erow = it_tab + (long long)r * CH;   // it_tab==item_emb here
  }

  int beg = row_ptr[row], end = row_ptr[row + 1];
  float4 acc = make_float4(0.f, 0.f, 0.f, 0.f);
  int j = beg + slot;
  // unrolled x2: two independent (csr, row) load pairs in flight
  for (; j + 4 < end; j += 8) {
    int2  e0 = csr[j];
    int2  e1 = csr[j + 4];
    float4 v0 = *(const float4*)(gtab + (long long)e0.x * CH + c4);
    float4 v1 = *(const float4*)(gtab + (long long)e1.x * CH + c4);
    float w0 = __int_as_float(e0.y);
    float w1 = __int_as_float(e1.y);
    acc.x += w0 * v0.x; acc.y += w0 * v0.y;
    acc.z += w0 * v0.z; acc.w += w0 * v0.w;
    acc.x += w1 * v1.x; acc.y += w1 * v1.y;
    acc.z += w1 * v1.z; acc.w += w1 * v1.w;
  }
  if (j < end) {
    int2  e  = csr[j];
    float we = __int_as_float(e.y);
    float4 v = *(const float4*)(gtab + (long long)e.x * CH + c4);
    acc.x += we * v.x; acc.y += we * v.y;
    acc.z += we * v.z; acc.w += we * v.w;
  }
  for (int off = 16; off < 64; off <<= 1) {
    acc.x += __shfl_xor(acc.x, off, 64);
    acc.y += __shfl_xor(acc.y, off, 64);
    acc.z += __shfl_xor(acc.z, off, 64);
    acc.w += __shfl_xor(acc.w, off, 64);
  }
  if (slot == 0) {
    if (MODE == 0) {
      float4 e4 = *(const float4*)(erow + c4);
      *(float4*)(drow + c4) = acc;
      e4.x += acc.x; e4.y += acc.y; e4.z += acc.z; e4.w += acc.w;
      *(float4*)(orow + c4) = e4;
    } else if (MODE == 1) {
      float4 o = *(const float4*)(orow + c4);
      *(float4*)(drow + c4) = acc;
      o.x += acc.x; o.y += acc.y; o.z += acc.z; o.w += acc.w;
      *(float4*)(orow + c4) = o;
    } else {
      const float s = 1.0f / (LAYERS + 1);
      float4 o = *(const float4*)(orow + c4);
      o.x = (o.x + acc.x) * s; o.y = (o.y + acc.y) * s;
      o.z = (o.z + acc.z) * s; o.w = (o.w + acc.w) * s;
      *(float4*)(orow + c4) = o;
    }
  }
}

// ---------------- fallback (R1 atomic path) ----------------

__global__ __launch_bounds__(256) void atomic_scatter_kernel(
    const float* __restrict__ src, float* __restrict__ dst,
    const int* __restrict__ u_idx, const int* __restrict__ i_idx,
    const float* __restrict__ w) {
  long long tid = (long long)blockIdx.x * blockDim.x + threadIdx.x;
  int edge = (int)(tid >> 4);
  if (edge >= N_EDGES) return;
  int c = ((int)tid & 15) * 4;
  int ui = u_idx[edge], ii = i_idx[edge];
  float we = w[edge];
  float4 itv = *(const float4*)(src + (long long)ii * CH + c);
  float4 uv  = *(const float4*)(src + ITEM_ELEMS + (long long)ui * CH + c);
  float* ud = dst + ITEM_ELEMS + (long long)ui * CH + c;
  float* id = dst + (long long)ii * CH + c;
  unsafeAtomicAdd(ud + 0, we * itv.x);
  unsafeAtomicAdd(ud + 1, we * itv.y);
  unsafeAtomicAdd(ud + 2, we * itv.z);
  unsafeAtomicAdd(ud + 3, we * itv.w);
  unsafeAtomicAdd(id + 0, we * uv.x);
  unsafeAtomicAdd(id + 1, we * uv.y);
  unsafeAtomicAdd(id + 2, we * uv.z);
  unsafeAtomicAdd(id + 3, we * uv.w);
}

__global__ __launch_bounds__(256) void add_scale_kernel(
    float* __restrict__ acc, const float* __restrict__ add, float s, long long n4) {
  long long i = (long long)blockIdx.x * blockDim.x + threadIdx.x;
  if (i >= n4) return;
  float4 a = ((const float4*)acc)[i];
  float4 b = ((const float4*)add)[i];
  a.x = (a.x + b.x) * s;
  a.y = (a.y + b.y) * s;
  a.z = (a.z + b.z) * s;
  a.w = (a.w + b.w) * s;
  ((float4*)acc)[i] = a;
}

extern "C" void kernel_launch(void* const* d_in, const int* in_sizes, int n_in,
                              void* d_out, int out_size, void* d_ws, size_t ws_size,
                              hipStream_t stream) {
  const float* user_emb = (const float*)d_in[1];
  const float* item_emb = (const float*)d_in[2];
  const int*   edges    = (const int*)d_in[3];
  const int*   u_idx    = edges;            // row 0
  const int*   i_idx    = edges + N_EDGES;  // row 1
  const float* w        = (const float*)d_in[4];

  float* out = (float*)d_out;  // [item_acc | user_acc]

  // workspace layout (4B units) — offsets kept identical to R8
  float* buf_a   = (float*)d_ws;                 // TOT_ELEMS
  float* buf_b   = buf_a + TOT_ELEMS;            // TOT_ELEMS
  int2*  csr     = (int2*)(buf_b + TOT_ELEMS);   // NDIR int2
  int*   ibase   = (int*)(csr + NDIR);           // NROWS (spare)
  int*   row_ptr = ibase + NROWS;                // NROWS + 1
  const size_t needed =
      ((size_t)2 * TOT_ELEMS + 2 * (size_t)NDIR + 3 * (size_t)NROWS + 1 + 1024) * 4;

  // transient aliases (dead before their hosts are written):
  //   seg aliases buf_a (gather L1 writes buf_a AFTER win_place)
  //   blkwin/segoff/hist2/cnt_slot alias buf_b (gather L2 writes buf_b later)
  int2* seg      = (int2*)buf_a;                 // NDIR int2 = 32MB <= 38.4MB
  int*  blkwin   = (int*)buf_b;                  // NWQ (250112)
  int*  segoff   = blkwin + NWQ;                 // NWQ
  int*  blksums2 = segoff + NWQ;                 // 1024
  int*  hist2    = blksums2 + 1024;              // H2SZ (2,400,256)
  int*  cnt_slot = hist2 + H2SZ;                 // NSLOT (150016)
  int*  blksums3 = cnt_slot + NSLOT;             // 1024
  // total buf_b use: ~12.2 MB of 38.4 MB

  if (ws_size >= needed) {
    // ---- CSR build (zero device atomics) ----
    bincnt_kernel<<<QBLK, 256, 0, stream>>>(u_idx, i_idx, blkwin);
    const int nblocksW = (NWQ + 255) / 256;   // 977 <= 1024
    scanA_kernel<<<nblocksW, 256, 0, stream>>>(blkwin, segoff, blksums2, NWQ);
    scanB_kernel<<<1, 1024, 0, stream>>>(blksums2, nblocksW);
    winscanC_kernel<<<nblocksW, 256, 0, stream>>>(segoff, blksums2, NWQ);
    seg_write<<<QBLK, 256, 0, stream>>>(u_idx, i_idx, w, segoff, seg);
    // full-chip counting sort
    win_hist<<<SORTWG, 1024, 0, stream>>>(seg, segoff, hist2);
    const int nblocksS = (NSLOT + 255) / 256;  // 586
    chunk_scan<<<nblocksS, 256, 0, stream>>>(hist2, cnt_slot);
    scanA_kernel<<<nblocksS, 256, 0, stream>>>(cnt_slot, cnt_slot, blksums3, NSLOT);
    scanB_kernel<<<1, 1024, 0, stream>>>(blksums3, nblocksS);
    rowptrC_kernel<<<nblocksS, 256, 0, stream>>>(cnt_slot, blksums3, row_ptr);
    win_place<<<SORTWG, 1024, 0, stream>>>(seg, segoff, hist2, row_ptr, csr);

    // ---- layers (gather + fused residual) ----
    const int gather_blocks = (NROWS + 3) / 4;  // 4 rows (waves) per block
    // L1: gather from input tables; out = emb + l1; buf_a = l1
    gather_fused<0><<<gather_blocks, 256, 0, stream>>>(
        item_emb, user_emb, buf_a, out, csr, row_ptr);
    // L2: gather from buf_a; out += l2; buf_b = l2
    gather_fused<1><<<gather_blocks, 256, 0, stream>>>(
        buf_a, buf_a + ITEM_ELEMS, buf_b, out, csr, row_ptr);
    // L3: gather from buf_b; out = (out + l3) * 0.25
    gather_fused<2><<<gather_blocks, 256, 0, stream>>>(
        buf_b, buf_b + ITEM_ELEMS, nullptr, out, csr, row_ptr);
  } else {
    // ---- fallback: R1 atomic scatter ----
    const size_t item_bytes = (size_t)ITEM_ELEMS * sizeof(float);
    const size_t user_bytes = (size_t)USER_ELEMS * sizeof(float);
    hipMemcpyAsync(buf_a,              item_emb, item_bytes, hipMemcpyDeviceToDevice, stream);
    hipMemcpyAsync(buf_a + ITEM_ELEMS, user_emb, user_bytes, hipMemcpyDeviceToDevice, stream);
    hipMemcpyAsync(out,                item_emb, item_bytes, hipMemcpyDeviceToDevice, stream);
    hipMemcpyAsync(out + ITEM_ELEMS,   user_emb, user_bytes, hipMemcpyDeviceToDevice, stream);
    const long long st = (long long)N_EDGES * 16;
    const int sb = (int)((st + 255) / 256);
    const long long n4 = TOT_ELEMS / 4;
    const int add_blocks = (int)((n4 + 255) / 256);
    float* src = buf_a;
    float* dst = buf_b;
    for (int l = 0; l < LAYERS; ++l) {
      hipMemsetAsync(dst, 0, (size_t)TOT_ELEMS * sizeof(float), stream);
      atomic_scatter_kernel<<<sb, 256, 0, stream>>>(src, dst, u_idx, i_idx, w);
      const float s = (l == LAYERS - 1) ? (1.0f / (LAYERS + 1)) : 1.0f;
      add_scale_kernel<<<add_blocks, 256, 0, stream>>>(out, dst, s, n4);
      float* t = src; src = dst; dst = t;
    }
  }
}

// Round 5
// 523.461 us; speedup vs baseline: 1.6633x; 1.2100x over previous
//
#include <hip/hip_runtime.h>

// AttnHGCN.forward_ui — 3-layer bipartite LightGCN-style propagation.
// R10: fp16 gather tables. R9 counters: gather_fused = 3x143us with
//     FETCH_SIZE 441MB vs ~110MB compulsory — the excess is random-gather
//     miss traffic (4M x 256B row reads; every source row needed by all 8
//     XCDs; per-XCD 4MB L2 holds ~10% of the 38.4MB tables). Writes are
//     already perfect (75MB = payload). Halve the bytes: store inter-layer
//     tables + an fp16 copy of the inputs as _Float16 -> one 128B cache
//     line per edge-gather (vs two), halving request count and miss bytes.
//     fp16 RN err (2^-11 rel) propagates to ~1e-2 max final error < 0.03125
//     tolerance (bf16 would be borderline). `out` accumulation stays fp32.
//     CSR build unchanged (R9 full-chip counting sort, zero device atomics).

constexpr int N_USERS = 100000;
constexpr int N_ITEMS = 50000;
constexpr int CH      = 64;
constexpr int N_EDGES = 2000000;
constexpr int LAYERS  = 3;
constexpr int NROWS   = N_USERS + N_ITEMS;          // 150000 combined dest rows
constexpr int NDIR    = 2 * N_EDGES;                // 4M directed edges

constexpr int QEDGES  = N_EDGES / 4;                // 500000 int4 edge-quads
constexpr int QBLK    = (QEDGES + 255) / 256;       // 1954 blocks over quads
constexpr int NWV     = QBLK * 4;                   // 7816 waves over quads

constexpr int WIN     = 32;                         // row windows
constexpr int WROWSW  = (NROWS + WIN - 1) / WIN;    // 4688 rows per window
constexpr int NWQ     = WIN * NWV;                  // 250112 (win,wave) counts

constexpr int CHUNKS  = 16;                         // segment chunks per window
constexpr int SORTWG  = WIN * CHUNKS;               // 512 sort workgroups
constexpr int NSLOT   = WIN * WROWSW;               // 150016 row slots
constexpr int H2SZ    = WIN * CHUNKS * WROWSW;      // 2,400,256 hist2 ints

constexpr long long ITEM_ELEMS = (long long)N_ITEMS * CH;  // 3,200,000
constexpr long long USER_ELEMS = (long long)N_USERS * CH;  // 6,400,000
constexpr long long TOT_ELEMS  = ITEM_ELEMS + USER_ELEMS;  // 9,600,000

typedef int      v4i __attribute__((ext_vector_type(4)));
typedef float    v4f __attribute__((ext_vector_type(4)));
typedef _Float16 v4h __attribute__((ext_vector_type(4)));

// ---------------- CSR build (zero device atomics) ----------------

// Per-(window, wave) end counts via shfl reduction. No early return: all
// lanes participate in the shfl reductions.
__global__ __launch_bounds__(256) void bincnt_kernel(
    const int* __restrict__ u_idx, const int* __restrict__ i_idx,
    int* __restrict__ blkwin) {
  int q = blockIdx.x * 256 + threadIdx.x;
  bool valid = (q < QEDGES);
  v4i u  = {0, 0, 0, 0};
  v4i it = {0, 0, 0, 0};
  if (valid) {
    u  = *(const v4i*)(u_idx + 4 * (long long)q);
    it = *(const v4i*)(i_idx + 4 * (long long)q);
  }
  int rows[8];
  if (valid) {
    rows[0] = u.x; rows[1] = u.y; rows[2] = u.z; rows[3] = u.w;
    rows[4] = N_USERS + it.x; rows[5] = N_USERS + it.y;
    rows[6] = N_USERS + it.z; rows[7] = N_USERS + it.w;
  } else {
#pragma unroll
    for (int k = 0; k < 8; ++k) rows[k] = -1;
  }
  int lane = threadIdx.x & 63;
  int gw   = blockIdx.x * 4 + (threadIdx.x >> 6);
#pragma unroll
  for (int win = 0; win < WIN; ++win) {
    const int wlo = win * WROWSW;
    int c = 0;
#pragma unroll
    for (int k = 0; k < 8; ++k)
      c += ((unsigned)(rows[k] - wlo) < (unsigned)WROWSW) ? 1 : 0;
#pragma unroll
    for (int d = 1; d < 64; d <<= 1) c += __shfl_xor(c, d, 64);
    if (lane == 0) blkwin[win * NWV + gw] = c;
  }
}

// per-256-block exclusive scan; block sums out (generic; in==out ok)
__global__ __launch_bounds__(256) void scanA_kernel(
    const int* __restrict__ in, int* __restrict__ out,
    int* __restrict__ blksums, int n) {
  __shared__ int sh[256];
  int t = threadIdx.x;
  int i = blockIdx.x * 256 + t;
  int v = (i < n) ? in[i] : 0;
  int x = v;
  sh[t] = x; __syncthreads();
  for (int d = 1; d < 256; d <<= 1) {
    int add = (t >= d) ? sh[t - d] : 0;
    __syncthreads();
    x += add; sh[t] = x;
    __syncthreads();
  }
  if (i < n) out[i] = x - v;  // exclusive within block
  if (t == 255) blksums[blockIdx.x] = x;
}

// single-block exclusive scan of block sums (n2 <= 1024)
__global__ __launch_bounds__(1024) void scanB_kernel(int* __restrict__ blksums, int n2) {
  __shared__ int sh[1024];
  int t = threadIdx.x;
  int v = (t < n2) ? blksums[t] : 0;
  int x = v;
  sh[t] = x; __syncthreads();
  for (int d = 1; d < 1024; d <<= 1) {
    int add = (t >= d) ? sh[t - d] : 0;
    __syncthreads();
    x += add; sh[t] = x;
    __syncthreads();
  }
  if (t < n2) blksums[t] = x - v;  // exclusive
}

// add block offsets (segment-offset variant)
__global__ __launch_bounds__(256) void winscanC_kernel(
    int* __restrict__ out, const int* __restrict__ blksums, int n) {
  int i = blockIdx.x * 256 + threadIdx.x;
  if (i < n) out[i] += blksums[i >> 8];
}

// Compact every directed end into its window's segment at a deterministic,
// wave-scanned position. All stores coalesced; zero atomics.
// Entry packing: x = (dstLow<<17) | src  (dstLow<4688 fits 13b, src<2^17),
//                y = float bits of w.
__global__ __launch_bounds__(256) void seg_write(
    const int* __restrict__ u_idx, const int* __restrict__ i_idx,
    const float* __restrict__ wv, const int* __restrict__ segoff,
    int2* __restrict__ seg) {
  int q = blockIdx.x * 256 + threadIdx.x;
  bool valid = (q < QEDGES);
  v4i u  = {0, 0, 0, 0};
  v4i it = {0, 0, 0, 0};
  v4f w  = {0.f, 0.f, 0.f, 0.f};
  if (valid) {
    u  = *(const v4i*)(u_idx + 4 * (long long)q);
    it = *(const v4i*)(i_idx + 4 * (long long)q);
    w  = *(const v4f*)(wv + 4 * (long long)q);
  }
  int rows[8], srcs[8], wbits[8];
  if (valid) {
    rows[0] = u.x; rows[1] = u.y; rows[2] = u.z; rows[3] = u.w;
    srcs[0] = it.x; srcs[1] = it.y; srcs[2] = it.z; srcs[3] = it.w;
    rows[4] = N_USERS + it.x; rows[5] = N_USERS + it.y;
    rows[6] = N_USERS + it.z; rows[7] = N_USERS + it.w;
    srcs[4] = u.x; srcs[5] = u.y; srcs[6] = u.z; srcs[7] = u.w;
    wbits[0] = __float_as_int(w.x); wbits[1] = __float_as_int(w.y);
    wbits[2] = __float_as_int(w.z); wbits[3] = __float_as_int(w.w);
    wbits[4] = wbits[0]; wbits[5] = wbits[1];
    wbits[6] = wbits[2]; wbits[7] = wbits[3];
  } else {
#pragma unroll
    for (int k = 0; k < 8; ++k) { rows[k] = -1; srcs[k] = 0; wbits[k] = 0; }
  }
  int lane = threadIdx.x & 63;
  int gw   = blockIdx.x * 4 + (threadIdx.x >> 6);
#pragma unroll
  for (int win = 0; win < WIN; ++win) {
    const int wlo = win * WROWSW;
    int c = 0;
#pragma unroll
    for (int k = 0; k < 8; ++k)
      c += ((unsigned)(rows[k] - wlo) < (unsigned)WROWSW) ? 1 : 0;
    // inclusive wave scan of c
    int x = c;
#pragma unroll
    for (int d = 1; d < 64; d <<= 1) {
      int y = __shfl_up(x, d, 64);
      if (lane >= d) x += y;
    }
    int pos = segoff[win * NWV + gw] + (x - c);  // exclusive prefix
#pragma unroll
    for (int k = 0; k < 8; ++k) {
      int dl = rows[k] - wlo;
      if ((unsigned)dl < (unsigned)WROWSW) {
        seg[pos++] = make_int2((dl << 17) | srcs[k], wbits[k]);
      }
    }
  }
}

// Phase 1: per-(window,chunk) LDS histogram of dstLow -> hist2 dump.
// win = blockIdx&31 so blockIdx%8 = win%8 (XCD pin, matters for phase 3).
__global__ __launch_bounds__(1024) void win_hist(
    const int2* __restrict__ seg, const int* __restrict__ segoff,
    int* __restrict__ hist2) {
  __shared__ int hist[WROWSW];   // 18752 B
  const int win   = blockIdx.x & 31;
  const int chunk = blockIdx.x >> 5;
  const int s0  = segoff[win * NWV];
  const int s1  = (win < WIN - 1) ? segoff[(win + 1) * NWV] : NDIR;
  const int csz = (s1 - s0 + CHUNKS - 1) / CHUNKS;
  const int c0  = s0 + chunk * csz;
  const int c1  = min(c0 + csz, s1);
  const int t   = threadIdx.x;
  for (int r = t; r < WROWSW; r += 1024) hist[r] = 0;
  __syncthreads();
  for (int idx = c0 + t; idx < c1; idx += 2048) {
    int i1 = idx + 1024;
    int x0 = seg[idx].x;
    int x1 = (i1 < c1) ? seg[i1].x : -1;
    atomicAdd(&hist[((unsigned)x0) >> 17], 1);
    if (x1 >= 0) atomicAdd(&hist[((unsigned)x1) >> 17], 1);
  }
  __syncthreads();
  int* hout = hist2 + (long long)(win * CHUNKS + chunk) * WROWSW;
  for (int r = t; r < WROWSW; r += 1024) hout[r] = hist[r];
}

// Phase 2: per row-slot, exclusive-prefix the CHUNKS counts in place;
// slot total -> cnt_slot. slot index == global row index (equal windows,
// padding slots at the very end).
__global__ __launch_bounds__(256) void chunk_scan(
    int* __restrict__ hist2, int* __restrict__ cnt_slot) {
  int i = blockIdx.x * 256 + threadIdx.x;
  if (i >= NSLOT) return;
  int win = i / WROWSW;
  int dl  = i - win * WROWSW;
  int* h = hist2 + (long long)win * CHUNKS * WROWSW + dl;
  int run = 0;
#pragma unroll
  for (int c = 0; c < CHUNKS; ++c) {
    long long o = (long long)c * WROWSW;
    int v = h[o];
    h[o] = run;
    run += v;
  }
  cnt_slot[i] = run;
}

// finalize row_ptr from the scanned cnt_slot (+ terminator)
__global__ __launch_bounds__(256) void rowptrC_kernel(
    const int* __restrict__ cnt_exc, const int* __restrict__ blksums,
    int* __restrict__ row_ptr) {
  int i = blockIdx.x * 256 + threadIdx.x;
  if (i < NROWS) row_ptr[i] = cnt_exc[i] + blksums[i >> 8];
  if (i == 0) row_ptr[NROWS] = NDIR;
}

// Phase 3: placement. LDS cursor = row_ptr[row] + per-chunk prefix; each
// chunk WG owns a disjoint slice of every row's CSR run -> LDS atomics
// only, positions globally unique. XCD-pinned per window (win = blk&31).
__global__ __launch_bounds__(1024) void win_place(
    const int2* __restrict__ seg, const int* __restrict__ segoff,
    const int* __restrict__ hist2, const int* __restrict__ row_ptr,
    int2* __restrict__ csr) {
  __shared__ int cur[WROWSW];    // 18752 B
  const int win   = blockIdx.x & 31;
  const int chunk = blockIdx.x >> 5;
  const int wlo = win * WROWSW;
  const int wsz = min(WROWSW, NROWS - wlo);
  const int s0  = segoff[win * NWV];
  const int s1  = (win < WIN - 1) ? segoff[(win + 1) * NWV] : NDIR;
  const int csz = (s1 - s0 + CHUNKS - 1) / CHUNKS;
  const int c0  = s0 + chunk * csz;
  const int c1  = min(c0 + csz, s1);
  const int t   = threadIdx.x;
  const int* hin = hist2 + (long long)(win * CHUNKS + chunk) * WROWSW;
  for (int r = t; r < wsz; r += 1024) cur[r] = row_ptr[wlo + r] + hin[r];
  __syncthreads();
  for (int idx = c0 + t; idx < c1; idx += 2048) {
    int i1 = idx + 1024;
    int2 e0 = seg[idx];
    int2 e1 = (i1 < c1) ? seg[i1] : make_int2(-1, 0);
    {
      int p = atomicAdd(&cur[((unsigned)e0.x) >> 17], 1);
      csr[p] = make_int2(e0.x & 0x1FFFF, e0.y);
    }
    if (e1.x >= 0) {
      int p = atomicAdd(&cur[((unsigned)e1.x) >> 17], 1);
      csr[p] = make_int2(e1.x & 0x1FFFF, e1.y);
    }
  }
}

// ---------------- fp16 table conversion ----------------
// t0[item | user] fp16 copy of the input embeddings (one 128B line per row).
__global__ __launch_bounds__(256) void cvt_tab(
    const float* __restrict__ it, const float* __restrict__ u,
    _Float16* __restrict__ t0) {
  long long i = (long long)blockIdx.x * 256 + threadIdx.x;  // float4 quads
  if (i >= TOT_ELEMS / 4) return;
  long long e = i * 4;
  const float* src = (e < ITEM_ELEMS) ? (it + e) : (u + (e - ITEM_ELEMS));
  v4f f = *(const v4f*)src;
  v4h h = {(_Float16)f.x, (_Float16)f.y, (_Float16)f.z, (_Float16)f.w};
  *(v4h*)(t0 + e) = h;
}

// ---------------- per-layer fused gather (fp16 sources) ----------------
// One wave per destination row; lane = slot(2b) x chan16(4b); adjacency loop
// unrolled x2 -> 8 edges (8x128B line gathers) in flight per wave;
// butterfly-reduce slots. Gather table is fp16 (one cache line per row);
// accumulation + `out` stay fp32. Epilogue fuses residual accumulation:
//   MODE 0 (layer 1):   dst = fp16(acc);  out = emb + acc
//   MODE 1 (mid layer): dst = fp16(acc);  out += acc
//   MODE 2 (last):                        out = (out + acc) * 1/(LAYERS+1)
template <int MODE>
__global__ __launch_bounds__(256) void gather_fused(
    const _Float16* __restrict__ tab,   // fp16 [item | user] gather table
    const float* __restrict__ emb_it,   // fp32 item_emb (MODE 0 residual)
    const float* __restrict__ emb_u,    // fp32 user_emb (MODE 0 residual)
    _Float16* __restrict__ dst,         // fp16 [item | user] layer out (MODE<2)
    float* __restrict__ out,            // fp32 [item_acc | user_acc]
    const int2* __restrict__ csr,
    const int* __restrict__ row_ptr) {
  int row = blockIdx.x * 4 + (threadIdx.x >> 6);
  if (row >= NROWS) return;
  int lane = threadIdx.x & 63;
  int slot = lane >> 4;          // 0..3
  int c4   = (lane & 15) * 4;    // channel offset 0..60

  const _Float16* gtab;          // opposite-side table to gather from
  const float* erow = nullptr;   // dest-side input-emb row (MODE 0)
  _Float16* drow = nullptr;
  float* orow;
  if (row < N_USERS) {
    gtab = tab;                                        // item side (base 0)
    orow = out + ITEM_ELEMS + (long long)row * CH;
    if (MODE < 2)  drow = dst + ITEM_ELEMS + (long long)row * CH;
    if (MODE == 0) erow = emb_u + (long long)row * CH;
  } else {
    int r = row - N_USERS;
    gtab = tab + ITEM_ELEMS;                           // user side
    orow = out + (long long)r * CH;
    if (MODE < 2)  drow = dst + (long long)r * CH;
    if (MODE == 0) erow = emb_it + (long long)r * CH;
  }

  int beg = row_ptr[row], end = row_ptr[row + 1];
  float4 acc = make_float4(0.f, 0.f, 0.f, 0.f);
  int j = beg + slot;
  // unrolled x2: two independent (csr, row) load pairs in flight
  for (; j + 4 < end; j += 8) {
    int2 e0 = csr[j];
    int2 e1 = csr[j + 4];
    v4h h0 = *(const v4h*)(gtab + (long long)e0.x * CH + c4);
    v4h h1 = *(const v4h*)(gtab + (long long)e1.x * CH + c4);
    float w0 = __int_as_float(e0.y);
    float w1 = __int_as_float(e1.y);
    acc.x += w0 * (float)h0.x; acc.y += w0 * (float)h0.y;
    acc.z += w0 * (float)h0.z; acc.w += w0 * (float)h0.w;
    acc.x += w1 * (float)h1.x; acc.y += w1 * (float)h1.y;
    acc.z += w1 * (float)h1.z; acc.w += w1 * (float)h1.w;
  }
  if (j < end) {
    int2 e = csr[j];
    float we = __int_as_float(e.y);
    v4h h = *(const v4h*)(gtab + (long long)e.x * CH + c4);
    acc.x += we * (float)h.x; acc.y += we * (float)h.y;
    acc.z += we * (float)h.z; acc.w += we * (float)h.w;
  }
  for (int off = 16; off < 64; off <<= 1) {
    acc.x += __shfl_xor(acc.x, off, 64);
    acc.y += __shfl_xor(acc.y, off, 64);
    acc.z += __shfl_xor(acc.z, off, 64);
    acc.w += __shfl_xor(acc.w, off, 64);
  }
  if (slot == 0) {
    if (MODE < 2) {
      v4h hd = {(_Float16)acc.x, (_Float16)acc.y,
                (_Float16)acc.z, (_Float16)acc.w};
      *(v4h*)(drow + c4) = hd;
    }
    if (MODE == 0) {
      float4 e4 = *(const float4*)(erow + c4);
      e4.x += acc.x; e4.y += acc.y; e4.z += acc.z; e4.w += acc.w;
      *(float4*)(orow + c4) = e4;
    } else if (MODE == 1) {
      float4 o = *(const float4*)(orow + c4);
      o.x += acc.x; o.y += acc.y; o.z += acc.z; o.w += acc.w;
      *(float4*)(orow + c4) = o;
    } else {
      const float s = 1.0f / (LAYERS + 1);
      float4 o = *(const float4*)(orow + c4);
      o.x = (o.x + acc.x) * s; o.y = (o.y + acc.y) * s;
      o.z = (o.z + acc.z) * s; o.w = (o.w + acc.w) * s;
      *(float4*)(orow + c4) = o;
    }
  }
}

// ---------------- fallback (R1 atomic path) ----------------

__global__ __launch_bounds__(256) void atomic_scatter_kernel(
    const float* __restrict__ src, float* __restrict__ dst,
    const int* __restrict__ u_idx, const int* __restrict__ i_idx,
    const float* __restrict__ w) {
  long long tid = (long long)blockIdx.x * blockDim.x + threadIdx.x;
  int edge = (int)(tid >> 4);
  if (edge >= N_EDGES) return;
  int c = ((int)tid & 15) * 4;
  int ui = u_idx[edge], ii = i_idx[edge];
  float we = w[edge];
  float4 itv = *(const float4*)(src + (long long)ii * CH + c);
  float4 uv  = *(const float4*)(src + ITEM_ELEMS + (long long)ui * CH + c);
  float* ud = dst + ITEM_ELEMS + (long long)ui * CH + c;
  float* id = dst + (long long)ii * CH + c;
  unsafeAtomicAdd(ud + 0, we * itv.x);
  unsafeAtomicAdd(ud + 1, we * itv.y);
  unsafeAtomicAdd(ud + 2, we * itv.z);
  unsafeAtomicAdd(ud + 3, we * itv.w);
  unsafeAtomicAdd(id + 0, we * uv.x);
  unsafeAtomicAdd(id + 1, we * uv.y);
  unsafeAtomicAdd(id + 2, we * uv.z);
  unsafeAtomicAdd(id + 3, we * uv.w);
}

__global__ __launch_bounds__(256) void add_scale_kernel(
    float* __restrict__ acc, const float* __restrict__ add, float s, long long n4) {
  long long i = (long long)blockIdx.x * blockDim.x + threadIdx.x;
  if (i >= n4) return;
  float4 a = ((const float4*)acc)[i];
  float4 b = ((const float4*)add)[i];
  a.x = (a.x + b.x) * s;
  a.y = (a.y + b.y) * s;
  a.z = (a.z + b.z) * s;
  a.w = (a.w + b.w) * s;
  ((float4*)acc)[i] = a;
}

extern "C" void kernel_launch(void* const* d_in, const int* in_sizes, int n_in,
                              void* d_out, int out_size, void* d_ws, size_t ws_size,
                              hipStream_t stream) {
  const float* user_emb = (const float*)d_in[1];
  const float* item_emb = (const float*)d_in[2];
  const int*   edges    = (const int*)d_in[3];
  const int*   u_idx    = edges;            // row 0
  const int*   i_idx    = edges + N_EDGES;  // row 1
  const float* w        = (const float*)d_in[4];

  float* out = (float*)d_out;  // [item_acc | user_acc]

  // workspace layout (4B units) — offsets kept identical to R9
  float* buf_a   = (float*)d_ws;                 // TOT_ELEMS
  float* buf_b   = buf_a + TOT_ELEMS;            // TOT_ELEMS
  int2*  csr     = (int2*)(buf_b + TOT_ELEMS);   // NDIR int2
  int*   ibase   = (int*)(csr + NDIR);           // NROWS (spare)
  int*   row_ptr = ibase + NROWS;                // NROWS + 1
  const size_t needed =
      ((size_t)2 * TOT_ELEMS + 2 * (size_t)NDIR + 3 * (size_t)NROWS + 1 + 1024) * 4;

  // transient aliases (dead before their hosts are written):
  //   seg aliases buf_a (t0/t1 written AFTER win_place consumes seg)
  //   blkwin/segoff/hist2/cnt_slot alias buf_b (t2 written during L2 gather,
  //   after the build phase is done with them)
  int2* seg      = (int2*)buf_a;                 // NDIR int2 = 32MB <= 38.4MB
  int*  blkwin   = (int*)buf_b;                  // NWQ (250112)
  int*  segoff   = blkwin + NWQ;                 // NWQ
  int*  blksums2 = segoff + NWQ;                 // 1024
  int*  hist2    = blksums2 + 1024;              // H2SZ (2,400,256)
  int*  cnt_slot = hist2 + H2SZ;                 // NSLOT (150016)
  int*  blksums3 = cnt_slot + NSLOT;             // 1024
  // fp16 tables (19.2MB each): t0+t1 fill buf_a exactly; t2 in buf_b
  _Float16* t0 = (_Float16*)buf_a;               // TOT_ELEMS halves
  _Float16* t1 = t0 + TOT_ELEMS;                 // TOT_ELEMS halves
  _Float16* t2 = (_Float16*)buf_b;               // TOT_ELEMS halves

  if (ws_size >= needed) {
    // ---- CSR build (zero device atomics) ----
    bincnt_kernel<<<QBLK, 256, 0, stream>>>(u_idx, i_idx, blkwin);
    const int nblocksW = (NWQ + 255) / 256;   // 977 <= 1024
    scanA_kernel<<<nblocksW, 256, 0, stream>>>(blkwin, segoff, blksums2, NWQ);
    scanB_kernel<<<1, 1024, 0, stream>>>(blksums2, nblocksW);
    winscanC_kernel<<<nblocksW, 256, 0, stream>>>(segoff, blksums2, NWQ);
    seg_write<<<QBLK, 256, 0, stream>>>(u_idx, i_idx, w, segoff, seg);
    // full-chip counting sort
    win_hist<<<SORTWG, 1024, 0, stream>>>(seg, segoff, hist2);
    const int nblocksS = (NSLOT + 255) / 256;  // 586
    chunk_scan<<<nblocksS, 256, 0, stream>>>(hist2, cnt_slot);
    scanA_kernel<<<nblocksS, 256, 0, stream>>>(cnt_slot, cnt_slot, blksums3, NSLOT);
    scanB_kernel<<<1, 1024, 0, stream>>>(blksums3, nblocksS);
    rowptrC_kernel<<<nblocksS, 256, 0, stream>>>(cnt_slot, blksums3, row_ptr);
    win_place<<<SORTWG, 1024, 0, stream>>>(seg, segoff, hist2, row_ptr, csr);

    // ---- fp16 input table (seg is dead now) ----
    const int cvt_blocks = (int)((TOT_ELEMS / 4 + 255) / 256);
    cvt_tab<<<cvt_blocks, 256, 0, stream>>>(item_emb, user_emb, t0);

    // ---- layers (gather + fused residual) ----
    const int gather_blocks = (NROWS + 3) / 4;  // 4 rows (waves) per block
    // L1: gather from t0; out = emb + l1; t1 = fp16(l1)
    gather_fused<0><<<gather_blocks, 256, 0, stream>>>(
        t0, item_emb, user_emb, t1, out, csr, row_ptr);
    // L2: gather from t1; out += l2; t2 = fp16(l2)
    gather_fused<1><<<gather_blocks, 256, 0, stream>>>(
        t1, nullptr, nullptr, t2, out, csr, row_ptr);
    // L3: gather from t2; out = (out + l3) * 0.25
    gather_fused<2><<<gather_blocks, 256, 0, stream>>>(
        t2, nullptr, nullptr, nullptr, out, csr, row_ptr);
  } else {
    // ---- fallback: R1 atomic scatter ----
    const size_t item_bytes = (size_t)ITEM_ELEMS * sizeof(float);
    const size_t user_bytes = (size_t)USER_ELEMS * sizeof(float);
    hipMemcpyAsync(buf_a,              item_emb, item_bytes, hipMemcpyDeviceToDevice, stream);
    hipMemcpyAsync(buf_a + ITEM_ELEMS, user_emb, user_bytes, hipMemcpyDeviceToDevice, stream);
    hipMemcpyAsync(out,                item_emb, item_bytes, hipMemcpyDeviceToDevice, stream);
    hipMemcpyAsync(out + ITEM_ELEMS,   user_emb, user_bytes, hipMemcpyDeviceToDevice, stream);
    const long long st = (long long)N_EDGES * 16;
    const int sb = (int)((st + 255) / 256);
    const long long n4 = TOT_ELEMS / 4;
    const int add_blocks = (int)((n4 + 255) / 256);
    float* src = buf_a;
    float* dst = buf_b;
    for (int l = 0; l < LAYERS; ++l) {
      hipMemsetAsync(dst, 0, (size_t)TOT_ELEMS * sizeof(float), stream);
      atomic_scatter_kernel<<<sb, 256, 0, stream>>>(src, dst, u_idx, i_idx, w);
      const float s = (l == LAYERS - 1) ? (1.0f / (LAYERS + 1)) : 1.0f;
      add_scale_kernel<<<add_blocks, 256, 0, stream>>>(out, dst, s, n4);
      float* t = src; src = dst; dst = t;
    }
  }
}

// Round 6
// 433.717 us; speedup vs baseline: 2.0074x; 1.2069x over previous
//
#include <hip/hip_runtime.h>

// AttnHGCN.forward_ui — 3-layer bipartite LightGCN-style propagation.
// R11: (a) gather: 8 lanes/row x 16B (v8h) instead of 16x8B -> 16 rows in
//     flight per wave (was 8), half the loop iterations; MODE0 residual
//     seeded from fp16 t0 (drops the 38.4MB fp32 emb read). R10 showed the
//     gather is request/latency-bound (bytes halved, dur only -30%).
//     (b) build: bincnt/seg_write rewritten from 32-window shfl-chain loops
//     (~450-700 VALU ops/thread, VALU-bound) to per-block LDS binning: 32
//     LDS counters/cursors (bank-spread), 8 LDS atomics/thread. Positions
//     remain globally unique via scanned per-(win,block) bases; within-block
//     order is atomic-scrambled (fp-sum noise only). Scan shrinks to
//     WIN*QBLK = 62528 elements.
//     Zero device-scope atomics (R8 lesson). Counting sort unchanged (R9).

constexpr int N_USERS = 100000;
constexpr int N_ITEMS = 50000;
constexpr int CH      = 64;
constexpr int N_EDGES = 2000000;
constexpr int LAYERS  = 3;
constexpr int NROWS   = N_USERS + N_ITEMS;          // 150000 combined dest rows
constexpr int NDIR    = 2 * N_EDGES;                // 4M directed edges

constexpr int QEDGES  = N_EDGES / 4;                // 500000 int4 edge-quads
constexpr int QBLK    = (QEDGES + 255) / 256;       // 1954 blocks over quads

constexpr int WIN     = 32;                         // row windows
constexpr int WROWSW  = (NROWS + WIN - 1) / WIN;    // 4688 rows per window
constexpr int NWQ2    = WIN * QBLK;                 // 62528 (win,block) counts

constexpr int CHUNKS  = 16;                         // segment chunks per window
constexpr int SORTWG  = WIN * CHUNKS;               // 512 sort workgroups
constexpr int NSLOT   = WIN * WROWSW;               // 150016 row slots
constexpr int H2SZ    = WIN * CHUNKS * WROWSW;      // 2,400,256 hist2 ints

constexpr long long ITEM_ELEMS = (long long)N_ITEMS * CH;  // 3,200,000
constexpr long long USER_ELEMS = (long long)N_USERS * CH;  // 6,400,000
constexpr long long TOT_ELEMS  = ITEM_ELEMS + USER_ELEMS;  // 9,600,000

typedef int      v4i __attribute__((ext_vector_type(4)));
typedef float    v4f __attribute__((ext_vector_type(4)));
typedef float    v8f __attribute__((ext_vector_type(8)));
typedef _Float16 v4h __attribute__((ext_vector_type(4)));
typedef _Float16 v8h __attribute__((ext_vector_type(8)));

// ---------------- CSR build (zero device atomics) ----------------

// Per-(window, block) end counts via LDS binning (32 counters, bank-spread).
__global__ __launch_bounds__(256) void bincnt_kernel(
    const int* __restrict__ u_idx, const int* __restrict__ i_idx,
    int* __restrict__ blkwin) {
  __shared__ int cnt[WIN];
  const int t = threadIdx.x;
  if (t < WIN) cnt[t] = 0;
  __syncthreads();
  int q = blockIdx.x * 256 + t;
  if (q < QEDGES) {
    v4i u  = *(const v4i*)(u_idx + 4 * (long long)q);
    v4i it = *(const v4i*)(i_idx + 4 * (long long)q);
    atomicAdd(&cnt[u.x / WROWSW], 1);
    atomicAdd(&cnt[u.y / WROWSW], 1);
    atomicAdd(&cnt[u.z / WROWSW], 1);
    atomicAdd(&cnt[u.w / WROWSW], 1);
    atomicAdd(&cnt[(N_USERS + it.x) / WROWSW], 1);
    atomicAdd(&cnt[(N_USERS + it.y) / WROWSW], 1);
    atomicAdd(&cnt[(N_USERS + it.z) / WROWSW], 1);
    atomicAdd(&cnt[(N_USERS + it.w) / WROWSW], 1);
  }
  __syncthreads();
  if (t < WIN) blkwin[t * QBLK + blockIdx.x] = cnt[t];
}

// per-256-block exclusive scan; block sums out (generic; in==out ok)
__global__ __launch_bounds__(256) void scanA_kernel(
    const int* __restrict__ in, int* __restrict__ out,
    int* __restrict__ blksums, int n) {
  __shared__ int sh[256];
  int t = threadIdx.x;
  int i = blockIdx.x * 256 + t;
  int v = (i < n) ? in[i] : 0;
  int x = v;
  sh[t] = x; __syncthreads();
  for (int d = 1; d < 256; d <<= 1) {
    int add = (t >= d) ? sh[t - d] : 0;
    __syncthreads();
    x += add; sh[t] = x;
    __syncthreads();
  }
  if (i < n) out[i] = x - v;  // exclusive within block
  if (t == 255) blksums[blockIdx.x] = x;
}

// single-block exclusive scan of block sums (n2 <= 1024)
__global__ __launch_bounds__(1024) void scanB_kernel(int* __restrict__ blksums, int n2) {
  __shared__ int sh[1024];
  int t = threadIdx.x;
  int v = (t < n2) ? blksums[t] : 0;
  int x = v;
  sh[t] = x; __syncthreads();
  for (int d = 1; d < 1024; d <<= 1) {
    int add = (t >= d) ? sh[t - d] : 0;
    __syncthreads();
    x += add; sh[t] = x;
    __syncthreads();
  }
  if (t < n2) blksums[t] = x - v;  // exclusive
}

// add block offsets (segment-offset variant)
__global__ __launch_bounds__(256) void winscanC_kernel(
    int* __restrict__ out, const int* __restrict__ blksums, int n) {
  int i = blockIdx.x * 256 + threadIdx.x;
  if (i < n) out[i] += blksums[i >> 8];
}

// Compact every directed end into its window's segment via per-block LDS
// cursors (base = scanned per-(win,block) count). Entry packing:
// x = (dstLow<<17) | src  (dstLow<4688 fits 13b, src<2^17), y = w bits.
__global__ __launch_bounds__(256) void seg_write(
    const int* __restrict__ u_idx, const int* __restrict__ i_idx,
    const float* __restrict__ wv, const int* __restrict__ segoff,
    int2* __restrict__ seg) {
  __shared__ int cur[WIN];
  const int t = threadIdx.x;
  if (t < WIN) cur[t] = segoff[t * QBLK + blockIdx.x];
  __syncthreads();
  int q = blockIdx.x * 256 + t;
  if (q >= QEDGES) return;
  v4i u  = *(const v4i*)(u_idx + 4 * (long long)q);
  v4i it = *(const v4i*)(i_idx + 4 * (long long)q);
  v4f w  = *(const v4f*)(wv + 4 * (long long)q);
#define PUT(ROW, SRC, WB)                              \
  {                                                    \
    int row = (ROW);                                   \
    int win = row / WROWSW;                            \
    int dl  = row - win * WROWSW;                      \
    int pos = atomicAdd(&cur[win], 1);                 \
    seg[pos] = make_int2((dl << 17) | (SRC), (WB));    \
  }
  PUT(u.x, it.x, __float_as_int(w.x))
  PUT(u.y, it.y, __float_as_int(w.y))
  PUT(u.z, it.z, __float_as_int(w.z))
  PUT(u.w, it.w, __float_as_int(w.w))
  PUT(N_USERS + it.x, u.x, __float_as_int(w.x))
  PUT(N_USERS + it.y, u.y, __float_as_int(w.y))
  PUT(N_USERS + it.z, u.z, __float_as_int(w.z))
  PUT(N_USERS + it.w, u.w, __float_as_int(w.w))
#undef PUT
}

// Phase 1: per-(window,chunk) LDS histogram of dstLow -> hist2 dump.
__global__ __launch_bounds__(1024) void win_hist(
    const int2* __restrict__ seg, const int* __restrict__ segoff,
    int* __restrict__ hist2) {
  __shared__ int hist[WROWSW];   // 18752 B
  const int win   = blockIdx.x & 31;
  const int chunk = blockIdx.x >> 5;
  const int s0  = segoff[win * QBLK];
  const int s1  = (win < WIN - 1) ? segoff[(win + 1) * QBLK] : NDIR;
  const int csz = (s1 - s0 + CHUNKS - 1) / CHUNKS;
  const int c0  = s0 + chunk * csz;
  const int c1  = min(c0 + csz, s1);
  const int t   = threadIdx.x;
  for (int r = t; r < WROWSW; r += 1024) hist[r] = 0;
  __syncthreads();
  for (int idx = c0 + t; idx < c1; idx += 2048) {
    int i1 = idx + 1024;
    int x0 = seg[idx].x;
    int x1 = (i1 < c1) ? seg[i1].x : -1;
    atomicAdd(&hist[((unsigned)x0) >> 17], 1);
    if (x1 >= 0) atomicAdd(&hist[((unsigned)x1) >> 17], 1);
  }
  __syncthreads();
  int* hout = hist2 + (long long)(win * CHUNKS + chunk) * WROWSW;
  for (int r = t; r < WROWSW; r += 1024) hout[r] = hist[r];
}

// Phase 2: per row-slot, exclusive-prefix the CHUNKS counts in place;
// slot total -> cnt_slot.
__global__ __launch_bounds__(256) void chunk_scan(
    int* __restrict__ hist2, int* __restrict__ cnt_slot) {
  int i = blockIdx.x * 256 + threadIdx.x;
  if (i >= NSLOT) return;
  int win = i / WROWSW;
  int dl  = i - win * WROWSW;
  int* h = hist2 + (long long)win * CHUNKS * WROWSW + dl;
  int run = 0;
#pragma unroll
  for (int c = 0; c < CHUNKS; ++c) {
    long long o = (long long)c * WROWSW;
    int v = h[o];
    h[o] = run;
    run += v;
  }
  cnt_slot[i] = run;
}

// finalize row_ptr from the scanned cnt_slot (+ terminator)
__global__ __launch_bounds__(256) void rowptrC_kernel(
    const int* __restrict__ cnt_exc, const int* __restrict__ blksums,
    int* __restrict__ row_ptr) {
  int i = blockIdx.x * 256 + threadIdx.x;
  if (i < NROWS) row_ptr[i] = cnt_exc[i] + blksums[i >> 8];
  if (i == 0) row_ptr[NROWS] = NDIR;
}

// Phase 3: placement. LDS cursor = row_ptr[row] + per-chunk prefix.
__global__ __launch_bounds__(1024) void win_place(
    const int2* __restrict__ seg, const int* __restrict__ segoff,
    const int* __restrict__ hist2, const int* __restrict__ row_ptr,
    int2* __restrict__ csr) {
  __shared__ int cur[WROWSW];    // 18752 B
  const int win   = blockIdx.x & 31;
  const int chunk = blockIdx.x >> 5;
  const int wlo = win * WROWSW;
  const int wsz = min(WROWSW, NROWS - wlo);
  const int s0  = segoff[win * QBLK];
  const int s1  = (win < WIN - 1) ? segoff[(win + 1) * QBLK] : NDIR;
  const int csz = (s1 - s0 + CHUNKS - 1) / CHUNKS;
  const int c0  = s0 + chunk * csz;
  const int c1  = min(c0 + csz, s1);
  const int t   = threadIdx.x;
  const int* hin = hist2 + (long long)(win * CHUNKS + chunk) * WROWSW;
  for (int r = t; r < wsz; r += 1024) cur[r] = row_ptr[wlo + r] + hin[r];
  __syncthreads();
  for (int idx = c0 + t; idx < c1; idx += 2048) {
    int i1 = idx + 1024;
    int2 e0 = seg[idx];
    int2 e1 = (i1 < c1) ? seg[i1] : make_int2(-1, 0);
    {
      int p = atomicAdd(&cur[((unsigned)e0.x) >> 17], 1);
      csr[p] = make_int2(e0.x & 0x1FFFF, e0.y);
    }
    if (e1.x >= 0) {
      int p = atomicAdd(&cur[((unsigned)e1.x) >> 17], 1);
      csr[p] = make_int2(e1.x & 0x1FFFF, e1.y);
    }
  }
}

// ---------------- fp16 table conversion ----------------
__global__ __launch_bounds__(256) void cvt_tab(
    const float* __restrict__ it, const float* __restrict__ u,
    _Float16* __restrict__ t0) {
  long long i = (long long)blockIdx.x * 256 + threadIdx.x;  // float4 quads
  if (i >= TOT_ELEMS / 4) return;
  long long e = i * 4;
  const float* src = (e < ITEM_ELEMS) ? (it + e) : (u + (e - ITEM_ELEMS));
  v4f f = *(const v4f*)src;
  v4h h = {(_Float16)f.x, (_Float16)f.y, (_Float16)f.z, (_Float16)f.w};
  *(v4h*)(t0 + e) = h;
}

// ---------------- per-layer fused gather (fp16 sources) ----------------
// One wave per destination row; 8 slots x 8 lanes; lane loads v8h (16B) of
// a 128B fp16 row -> 16 rows in flight per wave with unroll x2. Butterfly-
// reduce over slots (xor 8,16,32). acc + out stay fp32. Epilogue:
//   MODE 0: dst = fp16(acc); out = (float)t0row + acc   (fp16 residual seed)
//   MODE 1: dst = fp16(acc); out += acc
//   MODE 2:                  out = (out + acc) * 1/(LAYERS+1)
template <int MODE>
__global__ __launch_bounds__(256) void gather_fused(
    const _Float16* __restrict__ tab,   // fp16 [item | user] gather table
    _Float16* __restrict__ dst,         // fp16 [item | user] layer out (MODE<2)
    float* __restrict__ out,            // fp32 [item_acc | user_acc]
    const int2* __restrict__ csr,
    const int* __restrict__ row_ptr) {
  int row = blockIdx.x * 4 + (threadIdx.x >> 6);
  if (row >= NROWS) return;
  int lane = threadIdx.x & 63;
  int slot = lane >> 3;          // 0..7
  int c8   = (lane & 7) * 8;     // channel offset 0,8,...,56

  const _Float16* gtab;          // opposite-side table to gather from
  const _Float16* erow = nullptr;// own-side fp16 input row (MODE 0)
  _Float16* drow = nullptr;
  float* orow;
  if (row < N_USERS) {
    gtab = tab;                                        // item side (base 0)
    orow = out + ITEM_ELEMS + (long long)row * CH;
    if (MODE < 2)  drow = dst + ITEM_ELEMS + (long long)row * CH;
    if (MODE == 0) erow = tab + ITEM_ELEMS + (long long)row * CH;
  } else {
    int r = row - N_USERS;
    gtab = tab + ITEM_ELEMS;                           // user side
    orow = out + (long long)r * CH;
    if (MODE < 2)  drow = dst + (long long)r * CH;
    if (MODE == 0) erow = tab + (long long)r * CH;
  }

  int beg = row_ptr[row], end = row_ptr[row + 1];
  float acc[8];
#pragma unroll
  for (int k = 0; k < 8; ++k) acc[k] = 0.f;
  int j = beg + slot;
  // unroll x2: two independent (csr, row) load pairs in flight per slot
  for (; j + 8 < end; j += 16) {
    int2 e0 = csr[j];
    int2 e1 = csr[j + 8];
    v8h h0 = *(const v8h*)(gtab + (long long)e0.x * CH + c8);
    v8h h1 = *(const v8h*)(gtab + (long long)e1.x * CH + c8);
    float w0 = __int_as_float(e0.y);
    float w1 = __int_as_float(e1.y);
#pragma unroll
    for (int k = 0; k < 8; ++k) acc[k] += w0 * (float)h0[k];
#pragma unroll
    for (int k = 0; k < 8; ++k) acc[k] += w1 * (float)h1[k];
  }
  if (j < end) {
    int2 e = csr[j];
    float we = __int_as_float(e.y);
    v8h h = *(const v8h*)(gtab + (long long)e.x * CH + c8);
#pragma unroll
    for (int k = 0; k < 8; ++k) acc[k] += we * (float)h[k];
  }
#pragma unroll
  for (int off = 8; off < 64; off <<= 1) {
#pragma unroll
    for (int k = 0; k < 8; ++k) acc[k] += __shfl_xor(acc[k], off, 64);
  }
  if (slot == 0) {
    if (MODE < 2) {
      v8h hd;
#pragma unroll
      for (int k = 0; k < 8; ++k) hd[k] = (_Float16)acc[k];
      *(v8h*)(drow + c8) = hd;
    }
    if (MODE == 0) {
      v8h e8 = *(const v8h*)(erow + c8);
      v8f o;
#pragma unroll
      for (int k = 0; k < 8; ++k) o[k] = (float)e8[k] + acc[k];
      *(v8f*)(orow + c8) = o;
    } else if (MODE == 1) {
      v8f o = *(const v8f*)(orow + c8);
#pragma unroll
      for (int k = 0; k < 8; ++k) o[k] += acc[k];
      *(v8f*)(orow + c8) = o;
    } else {
      const float s = 1.0f / (LAYERS + 1);
      v8f o = *(const v8f*)(orow + c8);
#pragma unroll
      for (int k = 0; k < 8; ++k) o[k] = (o[k] + acc[k]) * s;
      *(v8f*)(orow + c8) = o;
    }
  }
}

// ---------------- fallback (R1 atomic path) ----------------

__global__ __launch_bounds__(256) void atomic_scatter_kernel(
    const float* __restrict__ src, float* __restrict__ dst,
    const int* __restrict__ u_idx, const int* __restrict__ i_idx,
    const float* __restrict__ w) {
  long long tid = (long long)blockIdx.x * blockDim.x + threadIdx.x;
  int edge = (int)(tid >> 4);
  if (edge >= N_EDGES) return;
  int c = ((int)tid & 15) * 4;
  int ui = u_idx[edge], ii = i_idx[edge];
  float we = w[edge];
  float4 itv = *(const float4*)(src + (long long)ii * CH + c);
  float4 uv  = *(const float4*)(src + ITEM_ELEMS + (long long)ui * CH + c);
  float* ud = dst + ITEM_ELEMS + (long long)ui * CH + c;
  float* id = dst + (long long)ii * CH + c;
  unsafeAtomicAdd(ud + 0, we * itv.x);
  unsafeAtomicAdd(ud + 1, we * itv.y);
  unsafeAtomicAdd(ud + 2, we * itv.z);
  unsafeAtomicAdd(ud + 3, we * itv.w);
  unsafeAtomicAdd(id + 0, we * uv.x);
  unsafeAtomicAdd(id + 1, we * uv.y);
  unsafeAtomicAdd(id + 2, we * uv.z);
  unsafeAtomicAdd(id + 3, we * uv.w);
}

__global__ __launch_bounds__(256) void add_scale_kernel(
    float* __restrict__ acc, const float* __restrict__ add, float s, long long n4) {
  long long i = (long long)blockIdx.x * blockDim.x + threadIdx.x;
  if (i >= n4) return;
  float4 a = ((const float4*)acc)[i];
  float4 b = ((const float4*)add)[i];
  a.x = (a.x + b.x) * s;
  a.y = (a.y + b.y) * s;
  a.z = (a.z + b.z) * s;
  a.w = (a.w + b.w) * s;
  ((float4*)acc)[i] = a;
}

extern "C" void kernel_launch(void* const* d_in, const int* in_sizes, int n_in,
                              void* d_out, int out_size, void* d_ws, size_t ws_size,
                              hipStream_t stream) {
  const float* user_emb = (const float*)d_in[1];
  const float* item_emb = (const float*)d_in[2];
  const int*   edges    = (const int*)d_in[3];
  const int*   u_idx    = edges;            // row 0
  const int*   i_idx    = edges + N_EDGES;  // row 1
  const float* w        = (const float*)d_in[4];

  float* out = (float*)d_out;  // [item_acc | user_acc]

  // workspace layout (4B units) — offsets kept identical to R10
  float* buf_a   = (float*)d_ws;                 // TOT_ELEMS
  float* buf_b   = buf_a + TOT_ELEMS;            // TOT_ELEMS
  int2*  csr     = (int2*)(buf_b + TOT_ELEMS);   // NDIR int2
  int*   ibase   = (int*)(csr + NDIR);           // NROWS (spare)
  int*   row_ptr = ibase + NROWS;                // NROWS + 1
  const size_t needed =
      ((size_t)2 * TOT_ELEMS + 2 * (size_t)NDIR + 3 * (size_t)NROWS + 1 + 1024) * 4;

  // transient aliases (dead before their hosts are written)
  int2* seg      = (int2*)buf_a;                 // NDIR int2 = 32MB <= 38.4MB
  int*  blkwin   = (int*)buf_b;                  // NWQ2 (62528)
  int*  segoff   = blkwin + NWQ2;                // NWQ2
  int*  blksums2 = segoff + NWQ2;                // 1024
  int*  hist2    = blksums2 + 1024;              // H2SZ (2,400,256)
  int*  cnt_slot = hist2 + H2SZ;                 // NSLOT (150016)
  int*  blksums3 = cnt_slot + NSLOT;             // 1024
  // fp16 tables (19.2MB each): t0+t1 fill buf_a exactly; t2 in buf_b
  _Float16* t0 = (_Float16*)buf_a;               // TOT_ELEMS halves
  _Float16* t1 = t0 + TOT_ELEMS;                 // TOT_ELEMS halves
  _Float16* t2 = (_Float16*)buf_b;               // TOT_ELEMS halves

  if (ws_size >= needed) {
    // ---- CSR build (zero device atomics) ----
    bincnt_kernel<<<QBLK, 256, 0, stream>>>(u_idx, i_idx, blkwin);
    const int nblocksW = (NWQ2 + 255) / 256;   // 245 <= 1024
    scanA_kernel<<<nblocksW, 256, 0, stream>>>(blkwin, segoff, blksums2, NWQ2);
    scanB_kernel<<<1, 1024, 0, stream>>>(blksums2, nblocksW);
    winscanC_kernel<<<nblocksW, 256, 0, stream>>>(segoff, blksums2, NWQ2);
    seg_write<<<QBLK, 256, 0, stream>>>(u_idx, i_idx, w, segoff, seg);
    // full-chip counting sort
    win_hist<<<SORTWG, 1024, 0, stream>>>(seg, segoff, hist2);
    const int nblocksS = (NSLOT + 255) / 256;  // 586
    chunk_scan<<<nblocksS, 256, 0, stream>>>(hist2, cnt_slot);
    scanA_kernel<<<nblocksS, 256, 0, stream>>>(cnt_slot, cnt_slot, blksums3, NSLOT);
    scanB_kernel<<<1, 1024, 0, stream>>>(blksums3, nblocksS);
    rowptrC_kernel<<<nblocksS, 256, 0, stream>>>(cnt_slot, blksums3, row_ptr);
    win_place<<<SORTWG, 1024, 0, stream>>>(seg, segoff, hist2, row_ptr, csr);

    // ---- fp16 input table (seg is dead now) ----
    const int cvt_blocks = (int)((TOT_ELEMS / 4 + 255) / 256);
    cvt_tab<<<cvt_blocks, 256, 0, stream>>>(item_emb, user_emb, t0);

    // ---- layers (gather + fused residual) ----
    const int gather_blocks = (NROWS + 3) / 4;  // 4 rows (waves) per block
    gather_fused<0><<<gather_blocks, 256, 0, stream>>>(
        t0, t1, out, csr, row_ptr);
    gather_fused<1><<<gather_blocks, 256, 0, stream>>>(
        t1, t2, out, csr, row_ptr);
    gather_fused<2><<<gather_blocks, 256, 0, stream>>>(
        t2, nullptr, out, csr, row_ptr);
  } else {
    // ---- fallback: R1 atomic scatter ----
    const size_t item_bytes = (size_t)ITEM_ELEMS * sizeof(float);
    const size_t user_bytes = (size_t)USER_ELEMS * sizeof(float);
    hipMemcpyAsync(buf_a,              item_emb, item_bytes, hipMemcpyDeviceToDevice, stream);
    hipMemcpyAsync(buf_a + ITEM_ELEMS, user_emb, user_bytes, hipMemcpyDeviceToDevice, stream);
    hipMemcpyAsync(out,                item_emb, item_bytes, hipMemcpyDeviceToDevice, stream);
    hipMemcpyAsync(out + ITEM_ELEMS,   user_emb, user_bytes, hipMemcpyDeviceToDevice, stream);
    const long long st = (long long)N_EDGES * 16;
    const int sb = (int)((st + 255) / 256);
    const long long n4 = TOT_ELEMS / 4;
    const int add_blocks = (int)((n4 + 255) / 256);
    float* src = buf_a;
    float* dst = buf_b;
    for (int l = 0; l < LAYERS; ++l) {
      hipMemsetAsync(dst, 0, (size_t)TOT_ELEMS * sizeof(float), stream);
      atomic_scatter_kernel<<<sb, 256, 0, stream>>>(src, dst, u_idx, i_idx, w);
      const float s = (l == LAYERS - 1) ? (1.0f / (LAYERS + 1)) : 1.0f;
      add_scale_kernel<<<add_blocks, 256, 0, stream>>>(out, dst, s, n4);
      float* t = src; src = dst; dst = t;
    }
  }
}